// Round 1
// baseline (3672.631 us; speedup 1.0000x reference)
//
#include <hip/hip_runtime.h>
#include <hip/hip_bf16.h>

// Problem constants (match reference init_kwargs)
#define BB 8
#define LL 512
#define DD 64
#define CC 8     // n_head
#define GG 64    // n_global
#define NITER 3

// ---------------------------------------------------------------------------
// q_z = softmax(Q_Z, axis=-1) * m1    — one 64-thread wave per (b,i) row
// ---------------------------------------------------------------------------
__global__ __launch_bounds__(64) void softmax_z_kernel(
    const float* __restrict__ in, const int* __restrict__ mask,
    float* __restrict__ out) {
  int row = blockIdx.x;  // b*L + i
  int t = threadIdx.x;
  float v = in[row * 64 + t];
  float m = v;
  for (int o = 32; o; o >>= 1) m = fmaxf(m, __shfl_xor(m, o));
  float e = __expf(v - m);
  float s = e;
  for (int o = 32; o; o >>= 1) s += __shfl_xor(s, o);
  float mi = (mask[row] != 0) ? 1.0f : 0.0f;
  out[row * 64 + t] = e / s * mi;
}

// ---------------------------------------------------------------------------
// t1[k,b,c,i,e] = sum_a q_z[b,i,a] * ternary[k,a,e,c]
// grid = K*B*C*(L/32) = 2048 blocks, 256 thr
// ---------------------------------------------------------------------------
__global__ __launch_bounds__(256) void t1_kernel(
    const float* __restrict__ q_z, const float* __restrict__ ternary,
    float* __restrict__ t1) {
  int blk = blockIdx.x;
  int ic = blk & 15, c = (blk >> 4) & 7, b = (blk >> 7) & 7, k = blk >> 10;
  __shared__ float tern_s[64][64];  // [a][e]
  __shared__ float qz_s[32][64];    // [il][a]
  int t = threadIdx.x;
  for (int p = t; p < 4096; p += 256) {
    int a = p >> 6, e = p & 63;
    tern_s[a][e] = ternary[((k * 64 + a) * 64 + e) * 8 + c];
  }
  int i0 = ic * 32;
  for (int p = t; p < 2048; p += 256) {
    int il = p >> 6, a = p & 63;
    qz_s[il][a] = q_z[(b * LL + i0 + il) * 64 + a];
  }
  __syncthreads();
  int e = t & 63, il0 = t >> 6;
  float acc[8];
#pragma unroll
  for (int s = 0; s < 8; s++) acc[s] = 0.f;
  for (int a = 0; a < 64; a++) {
    float tv = tern_s[a][e];
#pragma unroll
    for (int s = 0; s < 8; s++) acc[s] += qz_s[il0 + 4 * s][a] * tv;
  }
  size_t base = ((size_t)((k * BB + b) * CC + c)) * LL * 64;
#pragma unroll
  for (int s = 0; s < 8; s++) {
    int il = il0 + 4 * s;
    t1[base + (size_t)(i0 + il) * 64 + e] = acc[s];
  }
}

// ---------------------------------------------------------------------------
// Q_H[b,c,i,j] = F_H = dot64(t1[ksel,b,c,i,:], q_z[b,j,:]),
//   ksel = (j>i)?0:(j<i)?1:(zero)
// grid = B*C*8*8 tiles of 64x64
// ---------------------------------------------------------------------------
__global__ __launch_bounds__(256) void fh_kernel(
    const float* __restrict__ t1, const float* __restrict__ q_z,
    float* __restrict__ qh) {
  int blk = blockIdx.x;
  int jt = blk & 7, it = (blk >> 3) & 7, c = (blk >> 6) & 7, b = blk >> 9;
  __shared__ float t1s[2][64][65];
  __shared__ float qzs[64][65];
  int t = threadIdx.x;
  int i0 = it * 64, j0 = jt * 64;
  size_t ob = ((size_t)(b * CC + c) * LL + i0) * LL + j0;
  if (it != jt) {
    int k = (jt > it) ? 0 : 1;
    size_t tb = (((size_t)((k * BB + b) * CC + c)) * LL + i0) * 64;
    for (int p = t; p < 4096; p += 256) {
      int ir = p >> 6, e = p & 63;
      t1s[0][ir][e] = t1[tb + (size_t)ir * 64 + e];
    }
    for (int p = t; p < 4096; p += 256) {
      int jr = p >> 6, e = p & 63;
      qzs[jr][e] = q_z[(b * LL + j0 + jr) * 64 + e];
    }
    __syncthreads();
    int tx = t & 15, ty = t >> 4;
    float acc[4][4] = {};
    for (int e = 0; e < 64; e++) {
      float av[4], bv[4];
#pragma unroll
      for (int q = 0; q < 4; q++) av[q] = t1s[0][ty * 4 + q][e];
#pragma unroll
      for (int q = 0; q < 4; q++) bv[q] = qzs[tx * 4 + q][e];
#pragma unroll
      for (int q = 0; q < 4; q++)
#pragma unroll
        for (int r = 0; r < 4; r++) acc[q][r] += av[q] * bv[r];
    }
#pragma unroll
    for (int q = 0; q < 4; q++)
#pragma unroll
      for (int r = 0; r < 4; r++)
        qh[ob + (size_t)(ty * 4 + q) * LL + tx * 4 + r] = acc[q][r];
  } else {
    for (int k = 0; k < 2; k++) {
      size_t tb = (((size_t)((k * BB + b) * CC + c)) * LL + i0) * 64;
      for (int p = t; p < 4096; p += 256) {
        int ir = p >> 6, e = p & 63;
        t1s[k][ir][e] = t1[tb + (size_t)ir * 64 + e];
      }
    }
    for (int p = t; p < 4096; p += 256) {
      int jr = p >> 6, e = p & 63;
      qzs[jr][e] = q_z[(b * LL + j0 + jr) * 64 + e];
    }
    __syncthreads();
    for (int s = 0; s < 16; s++) {
      int p = t + 256 * s;
      int ir = p >> 6, jr = p & 63;
      float acc = 0.f;
      if (jr != ir) {
        int k = (jr > ir) ? 0 : 1;
        for (int e = 0; e < 64; e++) acc += t1s[k][ir][e] * qzs[jr][e];
      }
      qh[ob + (size_t)ir * LL + jr] = acc;
    }
  }
}

// ---------------------------------------------------------------------------
// q_h = softmax(Q_H, axis=-1) * m2    — in place; one block per (b,c,i) row
// ---------------------------------------------------------------------------
__global__ __launch_bounds__(256) void softmax_h_kernel(
    float* __restrict__ qh, const int* __restrict__ mask) {
  int row = blockIdx.x;  // (b*C + c)*L + i
  int i = row & 511;
  int b = row >> 12;
  int t = threadIdx.x;
  size_t base = (size_t)row * LL;
  float v0 = qh[base + t], v1 = qh[base + t + 256];
  __shared__ float red[8];
  float m = fmaxf(v0, v1);
  for (int o = 32; o; o >>= 1) m = fmaxf(m, __shfl_xor(m, o));
  int wid = t >> 6;
  if ((t & 63) == 0) red[wid] = m;
  __syncthreads();
  m = fmaxf(fmaxf(red[0], red[1]), fmaxf(red[2], red[3]));
  float e0 = __expf(v0 - m), e1 = __expf(v1 - m);
  float s = e0 + e1;
  for (int o = 32; o; o >>= 1) s += __shfl_xor(s, o);
  if ((t & 63) == 0) red[4 + wid] = s;
  __syncthreads();
  s = red[4] + red[5] + red[6] + red[7];
  float mi = (mask[b * LL + i] != 0) ? 1.f : 0.f;
  float mj0 = (mask[b * LL + t] != 0) ? 1.f : 0.f;
  float mj1 = (mask[b * LL + t + 256] != 0) ? 1.f : 0.f;
  float inv = 1.f / s;
  qh[base + t] = e0 * inv * mi * mj0;
  qh[base + t + 256] = e1 * inv * mi * mj1;
}

// ---------------------------------------------------------------------------
// q_g[b,i,g] = softmax_g( sum_a q_z[b,i,a]*gw[g,a] ) * m1
// grid = B*(L/32) = 128
// ---------------------------------------------------------------------------
__global__ __launch_bounds__(256) void qg_kernel(
    const float* __restrict__ q_z, const float* __restrict__ gw,
    const int* __restrict__ mask, float* __restrict__ q_g) {
  int blk = blockIdx.x;
  int ic = blk & 15, b = blk >> 4;
  __shared__ float gw_s[64][65];  // [g][a]
  __shared__ float qz_s[32][64];
  __shared__ float fg_s[32][65];
  int t = threadIdx.x;
  for (int p = t; p < 4096; p += 256) {
    int g = p >> 6, a = p & 63;
    gw_s[g][a] = gw[g * 64 + a];
  }
  int i0 = ic * 32;
  for (int p = t; p < 2048; p += 256) {
    int il = p >> 6, a = p & 63;
    qz_s[il][a] = q_z[(b * LL + i0 + il) * 64 + a];
  }
  __syncthreads();
  int g = t & 63, il0 = t >> 6;
#pragma unroll
  for (int s = 0; s < 8; s++) {
    int il = il0 + 4 * s;
    float acc = 0.f;
    for (int a = 0; a < 64; a++) acc += qz_s[il][a] * gw_s[g][a];
    fg_s[il][g] = acc;
  }
  __syncthreads();
  if (t < 32) {
    float m = -1e30f;
    for (int g2 = 0; g2 < 64; g2++) m = fmaxf(m, fg_s[t][g2]);
    float s = 0.f;
    for (int g2 = 0; g2 < 64; g2++) {
      float e = __expf(fg_s[t][g2] - m);
      fg_s[t][g2] = e;
      s += e;
    }
    float mi = (mask[b * LL + i0 + t] != 0) ? 1.f : 0.f;
    float inv = mi / s;
    for (int g2 = 0; g2 < 64; g2++)
      q_g[(b * LL + i0 + t) * 64 + g2] = fg_s[t][g2] * inv;
  }
}

// ---------------------------------------------------------------------------
// F1[b,i,a] += sum_{k,e} [ sum_j qh[b,c,i,j]*dm[k,i,j]*q_z[b,j,e] ] * T[k,a,e,c]
// one block per (b, i-tile of 32, c); atomic accumulate over c
// ---------------------------------------------------------------------------
__global__ __launch_bounds__(256) void f1_kernel(
    const float* __restrict__ qh, const float* __restrict__ q_z,
    const float* __restrict__ ternary, float* __restrict__ F1) {
  int blk = blockIdx.x;
  int c = blk & 7, it = (blk >> 3) & 15, b = blk >> 7;
  int i0 = it * 32;
  int t = threadIdx.x;
  __shared__ float smem[12288];  // 48 KB, phase-overlaid
  float(*qh_s)[64] = (float(*)[64])(smem);              // [32][64]
  float(*qz_s)[64] = (float(*)[64])(smem + 2048);       // [64][64]
  float(*tern_t)[64][64] = (float(*)[64][64])(smem);    // [2][e][a] overlay
  float(*a1_s)[32][64] = (float(*)[32][64])(smem + 8192);  // [2][32][64]

  float a1_0[8], a1_1[8];
#pragma unroll
  for (int s = 0; s < 8; s++) { a1_0[s] = 0.f; a1_1[s] = 0.f; }
  int e = t & 63, il0 = t >> 6;
  for (int jc = 0; jc < 8; jc++) {
    int j0 = jc * 64;
    __syncthreads();
    for (int p = t; p < 2048; p += 256) {
      int il = p >> 6, jl = p & 63;
      qh_s[il][jl] =
          qh[((size_t)(b * CC + c) * LL + i0 + il) * LL + j0 + jl];
    }
    for (int p = t; p < 4096; p += 256) {
      int jl = p >> 6, ee = p & 63;
      qz_s[jl][ee] = q_z[(b * LL + j0 + jl) * 64 + ee];
    }
    __syncthreads();
    for (int jl = 0; jl < 64; jl++) {
      int j = j0 + jl;
      float bz = qz_s[jl][e];
#pragma unroll
      for (int s = 0; s < 8; s++) {
        int i = i0 + il0 + 4 * s;
        float w = qh_s[il0 + 4 * s][jl] * bz;
        if (j > i) a1_0[s] += w;
        else if (j < i) a1_1[s] += w;
      }
    }
  }
  __syncthreads();  // all phase-1 reads done before overlay write
  for (int p = t; p < 8192; p += 256) {
    int k = p >> 12, rem = p & 4095;
    int ee = rem >> 6, a = rem & 63;
    tern_t[k][ee][a] = ternary[((k * 64 + a) * 64 + ee) * 8 + c];
  }
#pragma unroll
  for (int s = 0; s < 8; s++) {
    int il = il0 + 4 * s;
    a1_s[0][il][e] = a1_0[s];
    a1_s[1][il][e] = a1_1[s];
  }
  __syncthreads();
  int a = t & 63;
#pragma unroll
  for (int s = 0; s < 8; s++) {
    int il = il0 + 4 * s;
    float acc = 0.f;
    for (int ee = 0; ee < 64; ee++) {
      acc += a1_s[0][il][ee] * tern_t[0][ee][a] +
             a1_s[1][il][ee] * tern_t[1][ee][a];
    }
    atomicAdd(&F1[(b * LL + i0 + il) * 64 + a], acc);
  }
}

// ---------------------------------------------------------------------------
// F2[b,j,e] += sum_{k,a} [ sum_i qh[b,c,i,j]*dm[k,i,j]*q_z[b,i,a] ] * T[k,a,e,c]
// one block per (b, j-tile of 32, c)
// ---------------------------------------------------------------------------
__global__ __launch_bounds__(256) void f2_kernel(
    const float* __restrict__ qh, const float* __restrict__ q_z,
    const float* __restrict__ ternary, float* __restrict__ F2) {
  int blk = blockIdx.x;
  int c = blk & 7, jt = (blk >> 3) & 15, b = blk >> 7;
  int j0 = jt * 32;
  int t = threadIdx.x;
  __shared__ float smem[12288];
  float(*qh_s)[33] = (float(*)[33])(smem);                 // [64][33]
  float(*qz_s)[64] = (float(*)[64])(smem + 2112);          // [64][64]
  float(*tern_s)[64][64] = (float(*)[64][64])(smem);       // [2][a][e] overlay
  float(*a2_s)[32][64] = (float(*)[32][64])(smem + 8192);  // [2][32][64]

  float a2_0[8], a2_1[8];
#pragma unroll
  for (int s = 0; s < 8; s++) { a2_0[s] = 0.f; a2_1[s] = 0.f; }
  int a = t & 63, jl0 = t >> 6;
  for (int icnk = 0; icnk < 8; icnk++) {
    int ic0 = icnk * 64;
    __syncthreads();
    for (int p = t; p < 2048; p += 256) {
      int ii = p >> 5, jl = p & 31;
      qh_s[ii][jl] =
          qh[((size_t)(b * CC + c) * LL + ic0 + ii) * LL + j0 + jl];
    }
    for (int p = t; p < 4096; p += 256) {
      int ii = p >> 6, aa = p & 63;
      qz_s[ii][aa] = q_z[(b * LL + ic0 + ii) * 64 + aa];
    }
    __syncthreads();
    for (int ii = 0; ii < 64; ii++) {
      int i = ic0 + ii;
      float bz = qz_s[ii][a];
#pragma unroll
      for (int s = 0; s < 8; s++) {
        int j = j0 + jl0 + 4 * s;
        float w = qh_s[ii][jl0 + 4 * s] * bz;
        if (j > i) a2_0[s] += w;
        else if (j < i) a2_1[s] += w;
      }
    }
  }
  __syncthreads();
  for (int p = t; p < 8192; p += 256) {
    int k = p >> 12, rem = p & 4095;
    int aa = rem >> 6, ee = rem & 63;
    tern_s[k][aa][ee] = ternary[((k * 64 + aa) * 64 + ee) * 8 + c];
  }
#pragma unroll
  for (int s = 0; s < 8; s++) {
    int jl = jl0 + 4 * s;
    a2_s[0][jl][a] = a2_0[s];
    a2_s[1][jl][a] = a2_1[s];
  }
  __syncthreads();
  int e = t & 63;
#pragma unroll
  for (int s = 0; s < 8; s++) {
    int jl = jl0 + 4 * s;
    float acc = 0.f;
    for (int aa = 0; aa < 64; aa++) {
      acc += a2_s[0][jl][aa] * tern_s[0][aa][e] +
             a2_s[1][jl][aa] * tern_s[1][aa][e];
    }
    atomicAdd(&F2[(b * LL + j0 + jl) * 64 + e], acc);
  }
}

// ---------------------------------------------------------------------------
// Q_Z_new[b,i,a] = x + F1 + F2 + sum_g q_g[b,i,g]*gw[g,a]
// ---------------------------------------------------------------------------
__global__ __launch_bounds__(256) void fz_kernel(
    const float* __restrict__ x, const float* __restrict__ F1,
    const float* __restrict__ F2, const float* __restrict__ q_g,
    const float* __restrict__ gw, float* __restrict__ out) {
  int blk = blockIdx.x;
  int ic = blk & 15, b = blk >> 4;
  int i0 = ic * 32;
  int t = threadIdx.x;
  __shared__ float gw_s[64][65];  // [g][a]
  __shared__ float qg_s[32][64];
  for (int p = t; p < 4096; p += 256) {
    int g = p >> 6, a = p & 63;
    gw_s[g][a] = gw[g * 64 + a];
  }
  for (int p = t; p < 2048; p += 256) {
    int il = p >> 6, g = p & 63;
    qg_s[il][g] = q_g[(b * LL + i0 + il) * 64 + g];
  }
  __syncthreads();
  int a = t & 63, il0 = t >> 6;
#pragma unroll
  for (int s = 0; s < 8; s++) {
    int il = il0 + 4 * s;
    float acc = 0.f;
    for (int g = 0; g < 64; g++) acc += qg_s[il][g] * gw_s[g][a];
    size_t idx = (size_t)(b * LL + i0 + il) * 64 + a;
    out[idx] = x[idx] + F1[idx] + F2[idx] + acc;
  }
}

// ---------------------------------------------------------------------------
extern "C" void kernel_launch(void* const* d_in, const int* in_sizes, int n_in,
                              void* d_out, int out_size, void* d_ws,
                              size_t ws_size, hipStream_t stream) {
  const float* x = (const float*)d_in[0];
  const int* mask = (const int*)d_in[1];
  const float* ternary = (const float*)d_in[2];
  const float* gw = (const float*)d_in[3];
  float* out = (float*)d_out;

  float* ws = (float*)d_ws;
  float* q_z = ws;                      // 262144
  float* Q_Z = q_z + 262144;            // 262144
  float* t1 = Q_Z + 262144;             // 4194304
  float* qh = t1 + 4194304;             // 16777216
  float* q_g = qh + 16777216;           // 262144
  float* F1 = q_g + 262144;             // 262144
  float* F2 = F1 + 262144;              // 262144

  const float* zin = x;
  for (int iter = 0; iter < NITER; iter++) {
    softmax_z_kernel<<<BB * LL, 64, 0, stream>>>(zin, mask, q_z);
    t1_kernel<<<2048, 256, 0, stream>>>(q_z, ternary, t1);
    fh_kernel<<<4096, 256, 0, stream>>>(t1, q_z, qh);
    softmax_h_kernel<<<BB * CC * LL, 256, 0, stream>>>(qh, mask);
    qg_kernel<<<128, 256, 0, stream>>>(q_z, gw, mask, q_g);
    hipMemsetAsync(F1, 0, 262144 * sizeof(float), stream);
    hipMemsetAsync(F2, 0, 262144 * sizeof(float), stream);
    f1_kernel<<<1024, 256, 0, stream>>>(qh, q_z, ternary, F1);
    f2_kernel<<<1024, 256, 0, stream>>>(qh, q_z, ternary, F2);
    float* zout = (iter == NITER - 1) ? out : Q_Z;
    fz_kernel<<<128, 256, 0, stream>>>(x, F1, F2, q_g, gw, zout);
    zin = Q_Z;
  }
}

// Round 3
// 793.832 us; speedup vs baseline: 4.6265x; 4.6265x over previous
//
#include <hip/hip_runtime.h>
#include <hip/hip_bf16.h>

#define BB 8
#define LL 512
#define CC 8
#define NITER 3

typedef __attribute__((ext_vector_type(8))) short bf16x8;
typedef __attribute__((ext_vector_type(4))) float f32x4;
typedef unsigned short u16;

__device__ inline u16 f2b(float f) {
  __hip_bfloat16 h = __float2bfloat16(f);
  return *reinterpret_cast<u16*>(&h);
}
__device__ inline float b2f(u16 u) {
  __hip_bfloat16 h;
  *reinterpret_cast<u16*>(&h) = u;
  return __bfloat162float(h);
}
__device__ inline void split2(float v, u16& hi, u16& lo) {
  hi = f2b(v);
  lo = f2b(v - b2f(hi));
}

// Stage a [64][64] bf16 tile (row stride ld) into LDS, XOR-swizzled.
__device__ inline void stage64(u16* lds, const u16* __restrict__ src, int ld,
                               int t) {
  for (int ch = t; ch < 512; ch += 256) {
    int r = ch >> 3, seg = ch & 7;
    int byte = (r * 128 + seg * 16) ^ ((r & 7) << 4);
    *(bf16x8*)((char*)lds + byte) = *(const bf16x8*)(src + r * ld + seg * 8);
  }
}
// mfma_16x16x32 operand fragment from swizzled tile: rows row0..row0+15.
__device__ inline bf16x8 frag64(const u16* lds, int row0, int ks, int lane) {
  int r = row0 + (lane & 15);
  int byte = (r * 128 + ks * 64 + ((lane >> 4) << 4)) ^ ((r & 7) << 4);
  return *(const bf16x8*)((const char*)lds + byte);
}
// split-precision accumulate: acc += Ah*Bh + Ah*Bl + Al*Bh
__device__ inline void mfma3(f32x4& acc, bf16x8 ah, bf16x8 al, bf16x8 bh,
                             bf16x8 bl) {
  acc = __builtin_amdgcn_mfma_f32_16x16x32_bf16(ah, bh, acc, 0, 0, 0);
  acc = __builtin_amdgcn_mfma_f32_16x16x32_bf16(ah, bl, acc, 0, 0, 0);
  acc = __builtin_amdgcn_mfma_f32_16x16x32_bf16(al, bh, acc, 0, 0, 0);
}

#define ACC_INIT {{0.f,0.f,0.f,0.f},{0.f,0.f,0.f,0.f},{0.f,0.f,0.f,0.f},{0.f,0.f,0.f,0.f}}

// ---------------------------------------------------------------------------
// repack ternary to split pairs: TB[k,c][e][a], T1p[a][k,c,e], T2p[e][k,c,a]
// ---------------------------------------------------------------------------
__global__ __launch_bounds__(256) void repack_kernel(
    const float* __restrict__ T, u16* TBh, u16* TBl, u16* T1h, u16* T1l,
    u16* T2h, u16* T2l) {
  int tid = blockIdx.x * 256 + threadIdx.x;  // [2][64][64][8]
  int c = tid & 7, e = (tid >> 3) & 63, a = (tid >> 9) & 63, kk = tid >> 15;
  u16 hi, lo;
  split2(T[tid], hi, lo);
  int iTB = ((kk * 8 + c) * 64 + e) * 64 + a;
  int i1 = a * 1024 + kk * 512 + c * 64 + e;
  int i2 = e * 1024 + kk * 512 + c * 64 + a;
  TBh[iTB] = hi; TBl[iTB] = lo;
  T1h[i1] = hi;  T1l[i1] = lo;
  T2h[i2] = hi;  T2l[i2] = lo;
}

// ---------------------------------------------------------------------------
// q_z = softmax(Q_Z) * m1 ; fp32 + split-bf16 copies
// ---------------------------------------------------------------------------
__global__ __launch_bounds__(64) void softmax_z_kernel(
    const float* __restrict__ in, const int* __restrict__ mask,
    float* __restrict__ qz, u16* __restrict__ qzh, u16* __restrict__ qzl) {
  int row = blockIdx.x;
  int t = threadIdx.x;
  float v = in[row * 64 + t];
  float m = v;
  for (int o = 32; o; o >>= 1) m = fmaxf(m, __shfl_xor(m, o));
  float e = __expf(v - m);
  float s = e;
  for (int o = 32; o; o >>= 1) s += __shfl_xor(s, o);
  float mi = (mask[row] != 0) ? 1.f : 0.f;
  float r = e / s * mi;
  qz[row * 64 + t] = r;
  u16 hi, lo;
  split2(r, hi, lo);
  qzh[row * 64 + t] = hi;
  qzl[row * 64 + t] = lo;
}

// qzT[b][a][i] = qz[b][i][a]  (hi and lo)
__global__ __launch_bounds__(256) void qzT_kernel(
    const u16* __restrict__ qzh, const u16* __restrict__ qzl,
    u16* __restrict__ qzTh, u16* __restrict__ qzTl) {
  int blk = blockIdx.x;  // sel*64 + b*8 + it
  int it = blk & 7, b = (blk >> 3) & 7, sel = blk >> 6;
  const u16* src = sel ? qzl : qzh;
  u16* dst = sel ? qzTl : qzTh;
  __shared__ u16 s[64][65];
  int t = threadIdx.x;
  for (int p = t; p < 4096; p += 256) {
    int r = p >> 6, a = p & 63;
    s[r][a] = src[(b * 512 + it * 64 + r) * 64 + a];
  }
  __syncthreads();
  for (int p = t; p < 4096; p += 256) {
    int a = p >> 6, i = p & 63;
    dst[(b * 64 + a) * 512 + it * 64 + i] = s[i][a];
  }
}

// ---------------------------------------------------------------------------
// t1[kk,b,c][i][e] = sum_a qz[b,i,a] * T[kk,a,e,c]   (split out)
// ---------------------------------------------------------------------------
__global__ __launch_bounds__(256) void mm_t1_kernel(
    const u16* __restrict__ qzh, const u16* __restrict__ qzl,
    const u16* __restrict__ TBh, const u16* __restrict__ TBl,
    u16* __restrict__ t1h, u16* __restrict__ t1l) {
  int blk = blockIdx.x;  // kk*512 + b*64 + c*8 + it
  int it = blk & 7, c = (blk >> 3) & 7, b = (blk >> 6) & 7, kk = blk >> 9;
  __shared__ u16 ah_s[4096], al_s[4096], bh_s[4096], bl_s[4096];
  int t = threadIdx.x, lane = t & 63, w = t >> 6;
  stage64(ah_s, qzh + (b * 512 + it * 64) * 64, 64, t);
  stage64(al_s, qzl + (b * 512 + it * 64) * 64, 64, t);
  stage64(bh_s, TBh + (kk * 8 + c) * 4096, 64, t);
  stage64(bl_s, TBl + (kk * 8 + c) * 4096, 64, t);
  __syncthreads();
  f32x4 acc[4] = ACC_INIT;
  for (int ks = 0; ks < 2; ks++) {
    bf16x8 ah = frag64(ah_s, w * 16, ks, lane);
    bf16x8 al = frag64(al_s, w * 16, ks, lane);
#pragma unroll
    for (int nt = 0; nt < 4; nt++)
      mfma3(acc[nt], ah, al, frag64(bh_s, nt * 16, ks, lane),
            frag64(bl_s, nt * 16, ks, lane));
  }
  size_t base = ((size_t)((kk * 8 + b) * 8 + c)) * 32768;
  int rb = (lane >> 4) * 4, cl = lane & 15;
#pragma unroll
  for (int nt = 0; nt < 4; nt++)
#pragma unroll
    for (int r = 0; r < 4; r++) {
      size_t o = base + (size_t)(it * 64 + w * 16 + rb + r) * 64 + nt * 16 + cl;
      u16 h, l;
      split2(acc[nt][r], h, l);
      t1h[o] = h;
      t1l[o] = l;
    }
}

// ---------------------------------------------------------------------------
// per-row softmax stats over j of L[i][j] = t1[ksel(i,j)][i]·qz[j], diag=0.
// ---------------------------------------------------------------------------
__global__ __launch_bounds__(256) void stats_kernel(
    const u16* __restrict__ t1h, const u16* __restrict__ t1l,
    const u16* __restrict__ qzh, const u16* __restrict__ qzl,
    float* __restrict__ stm, float* __restrict__ sts) {
  int blk = blockIdx.x;  // b*64 + c*8 + it
  int it = blk & 7, c = (blk >> 3) & 7, b = blk >> 6;
  __shared__ u16 ts_[2][2][4096];
  __shared__ u16 qs[2][4096];
  int t = threadIdx.x, lane = t & 63, w = t >> 6, cl = lane & 15, g = lane >> 4;
  const size_t KSTR = (size_t)64 * 32768;
  size_t tb = ((size_t)(b * 8 + c)) * 32768 + it * 4096;
  stage64(ts_[0][0], t1h + tb, 64, t);
  stage64(ts_[0][1], t1l + tb, 64, t);
  stage64(ts_[1][0], t1h + tb + KSTR, 64, t);
  stage64(ts_[1][1], t1l + tb + KSTR, 64, t);
  float m[4] = {-1e30f, -1e30f, -1e30f, -1e30f};
  float s[4] = {0.f, 0.f, 0.f, 0.f};
  for (int jt = 0; jt < 8; jt++) {
    __syncthreads();
    stage64(qs[0], qzh + (b * 512 + jt * 64) * 64, 64, t);
    stage64(qs[1], qzl + (b * 512 + jt * 64) * 64, 64, t);
    __syncthreads();
    f32x4 acc0[4] = ACC_INIT;
    f32x4 acc1[4] = ACC_INIT;
    bool n0 = jt >= it, n1 = jt <= it;
    for (int ks = 0; ks < 2; ks++) {
      bf16x8 a0h = frag64(ts_[0][0], w * 16, ks, lane);
      bf16x8 a0l = frag64(ts_[0][1], w * 16, ks, lane);
      bf16x8 a1h = frag64(ts_[1][0], w * 16, ks, lane);
      bf16x8 a1l = frag64(ts_[1][1], w * 16, ks, lane);
#pragma unroll
      for (int nt = 0; nt < 4; nt++) {
        bf16x8 bh = frag64(qs[0], nt * 16, ks, lane);
        bf16x8 bl = frag64(qs[1], nt * 16, ks, lane);
        if (n0) mfma3(acc0[nt], a0h, a0l, bh, bl);
        if (n1) mfma3(acc1[nt], a1h, a1l, bh, bl);
      }
    }
    float Lv[4][4];
#pragma unroll
    for (int nt = 0; nt < 4; nt++)
#pragma unroll
      for (int r = 0; r < 4; r++) {
        int ig = it * 64 + w * 16 + g * 4 + r;
        int jg = jt * 64 + nt * 16 + cl;
        Lv[nt][r] = (jg > ig) ? acc0[nt][r] : ((jg < ig) ? acc1[nt][r] : 0.f);
      }
#pragma unroll
    for (int r = 0; r < 4; r++) {
      float tm = fmaxf(fmaxf(Lv[0][r], Lv[1][r]), fmaxf(Lv[2][r], Lv[3][r]));
      for (int o = 1; o < 16; o <<= 1) tm = fmaxf(tm, __shfl_xor(tm, o));
      float mn = fmaxf(m[r], tm);
      float ts = 0.f;
#pragma unroll
      for (int nt = 0; nt < 4; nt++) ts += __expf(Lv[nt][r] - mn);
      for (int o = 1; o < 16; o <<= 1) ts += __shfl_xor(ts, o);
      s[r] = s[r] * __expf(m[r] - mn) + ts;
      m[r] = mn;
    }
  }
  if (cl == 0) {
#pragma unroll
    for (int r = 0; r < 4; r++) {
      int i = it * 64 + w * 16 + g * 4 + r;
      stm[(b * 8 + c) * 512 + i] = m[r];
      sts[(b * 8 + c) * 512 + i] = s[r];
    }
  }
}

// ---------------------------------------------------------------------------
// A1[b][i][kk*512+c*64+e] = sum_j qh[kk][i][j]·qz[j][e]  (fused recompute)
// ---------------------------------------------------------------------------
__global__ __launch_bounds__(256) void a1_kernel(
    const u16* __restrict__ t1h, const u16* __restrict__ t1l,
    const u16* __restrict__ qzh, const u16* __restrict__ qzl,
    const u16* __restrict__ qzTh, const u16* __restrict__ qzTl,
    const float* __restrict__ stm, const float* __restrict__ sts,
    const int* __restrict__ mask, u16* __restrict__ A1h,
    u16* __restrict__ A1l) {
  int blk = blockIdx.x;  // b*64 + c*8 + it
  int it = blk & 7, c = (blk >> 3) & 7, b = blk >> 6;
  __shared__ u16 ts_[2][4096];  // t1[kk] hi/lo (per pass)
  __shared__ u16 bx[2][4096];   // qz[jt] hi/lo -> overlaid by qh hi/lo
  __shared__ u16 bt[2][4096];   // qzT j-chunk hi/lo
  int t = threadIdx.x, lane = t & 63, w = t >> 6, cl = lane & 15, g = lane >> 4;
  const size_t KSTR = (size_t)64 * 32768;
  size_t tb = ((size_t)(b * 8 + c)) * 32768 + it * 4096;
  int sbase = (b * 8 + c) * 512 + it * 64;
  float mrow[4], isrow[4], mi_[4];
#pragma unroll
  for (int r = 0; r < 4; r++) {
    int rl = w * 16 + g * 4 + r;
    mrow[r] = stm[sbase + rl];
    isrow[r] = 1.f / sts[sbase + rl];
    mi_[r] = (mask[b * 512 + it * 64 + rl] != 0) ? 1.f : 0.f;
  }
  f32x4 accA[2][4];
  for (int kk = 0; kk < 2; kk++)
    for (int nt = 0; nt < 4; nt++) accA[kk][nt] = (f32x4){0.f, 0.f, 0.f, 0.f};
  for (int jt = 0; jt < 8; jt++) {
    int k0 = (jt > it) ? 0 : 1;
    int npass = (jt == it) ? 2 : 1;
    for (int p = 0; p < npass; p++) {
      int kk = (jt == it) ? p : k0;
      __syncthreads();
      stage64(ts_[0], t1h + tb + (size_t)kk * KSTR, 64, t);
      stage64(ts_[1], t1l + tb + (size_t)kk * KSTR, 64, t);
      stage64(bx[0], qzh + (b * 512 + jt * 64) * 64, 64, t);
      stage64(bx[1], qzl + (b * 512 + jt * 64) * 64, 64, t);
      stage64(bt[0], qzTh + (size_t)b * 32768 + jt * 64, 512, t);
      stage64(bt[1], qzTl + (size_t)b * 32768 + jt * 64, 512, t);
      __syncthreads();
      f32x4 acc[4] = ACC_INIT;
      for (int ks = 0; ks < 2; ks++) {
        bf16x8 ah = frag64(ts_[0], w * 16, ks, lane);
        bf16x8 al = frag64(ts_[1], w * 16, ks, lane);
#pragma unroll
        for (int nt = 0; nt < 4; nt++)
          mfma3(acc[nt], ah, al, frag64(bx[0], nt * 16, ks, lane),
                frag64(bx[1], nt * 16, ks, lane));
      }
      __syncthreads();
#pragma unroll
      for (int nt = 0; nt < 4; nt++) {
        int jg = jt * 64 + nt * 16 + cl;
        float mj = (mask[b * 512 + jg] != 0) ? 1.f : 0.f;
#pragma unroll
        for (int r = 0; r < 4; r++) {
          int row = w * 16 + g * 4 + r;
          int ig = it * 64 + row;
          bool keep = (kk == 0) ? (jg > ig) : (jg < ig);
          float q = keep ? __expf(acc[nt][r] - mrow[r]) * isrow[r] * mi_[r] * mj
                         : 0.f;
          u16 h, l;
          split2(q, h, l);
          int byte = (row * 128 + (nt * 16 + cl) * 2) ^ ((row & 7) << 4);
          *(u16*)((char*)bx[0] + byte) = h;
          *(u16*)((char*)bx[1] + byte) = l;
        }
      }
      __syncthreads();
      for (int ks = 0; ks < 2; ks++) {
        bf16x8 ah = frag64(bx[0], w * 16, ks, lane);
        bf16x8 al = frag64(bx[1], w * 16, ks, lane);
#pragma unroll
        for (int nt = 0; nt < 4; nt++)
          mfma3(accA[kk][nt], ah, al, frag64(bt[0], nt * 16, ks, lane),
                frag64(bt[1], nt * 16, ks, lane));
      }
    }
  }
#pragma unroll
  for (int kk = 0; kk < 2; kk++)
#pragma unroll
    for (int nt = 0; nt < 4; nt++)
#pragma unroll
      for (int r = 0; r < 4; r++) {
        size_t o = ((size_t)b * 512 + it * 64 + w * 16 + g * 4 + r) * 1024 +
                   kk * 512 + c * 64 + nt * 16 + cl;
        u16 h, l;
        split2(accA[kk][nt][r], h, l);
        A1h[o] = h;
        A1l[o] = l;
      }
}

// ---------------------------------------------------------------------------
// A2[b][j][kk*512+c*64+a] = sum_i qh[kk][i][j]·qz[i][a]  (fused recompute)
// ---------------------------------------------------------------------------
__global__ __launch_bounds__(256) void a2_kernel(
    const u16* __restrict__ t1h, const u16* __restrict__ t1l,
    const u16* __restrict__ qzh, const u16* __restrict__ qzl,
    const u16* __restrict__ qzTh, const u16* __restrict__ qzTl,
    const float* __restrict__ stm, const float* __restrict__ sts,
    const int* __restrict__ mask, u16* __restrict__ A2h,
    u16* __restrict__ A2l) {
  int blk = blockIdx.x;  // b*64 + c*8 + jt
  int jt = blk & 7, c = (blk >> 3) & 7, b = blk >> 6;
  __shared__ u16 as_[2][4096];  // qz[jt] hi/lo (logit A)
  __shared__ u16 tsx[2][4096];  // t1 tile hi/lo -> overlaid by qhT
  __shared__ u16 bt[2][4096];   // qzT i-chunk hi/lo
  __shared__ float sm_s[64], si_s[64], mi_s[64];
  int t = threadIdx.x, lane = t & 63, w = t >> 6, cl = lane & 15, g = lane >> 4;
  const size_t KSTR = (size_t)64 * 32768;
  size_t tbb = ((size_t)(b * 8 + c)) * 32768;
  stage64(as_[0], qzh + (b * 512 + jt * 64) * 64, 64, t);
  stage64(as_[1], qzl + (b * 512 + jt * 64) * 64, 64, t);
  float mjrow[4];
#pragma unroll
  for (int r = 0; r < 4; r++) {
    int jg = jt * 64 + w * 16 + g * 4 + r;
    mjrow[r] = (mask[b * 512 + jg] != 0) ? 1.f : 0.f;
  }
  f32x4 accA[2][4];
  for (int kk = 0; kk < 2; kk++)
    for (int nt = 0; nt < 4; nt++) accA[kk][nt] = (f32x4){0.f, 0.f, 0.f, 0.f};
  for (int ii = 0; ii < 8; ii++) {
    int k0 = (ii < jt) ? 0 : 1;
    int npass = (ii == jt) ? 2 : 1;
    for (int p = 0; p < npass; p++) {
      int kk = (ii == jt) ? p : k0;
      __syncthreads();
      stage64(tsx[0], t1h + tbb + ii * 4096 + (size_t)kk * KSTR, 64, t);
      stage64(tsx[1], t1l + tbb + ii * 4096 + (size_t)kk * KSTR, 64, t);
      stage64(bt[0], qzTh + (size_t)b * 32768 + ii * 64, 512, t);
      stage64(bt[1], qzTl + (size_t)b * 32768 + ii * 64, 512, t);
      if (t < 64) {
        int ig = ii * 64 + t;
        sm_s[t] = stm[(b * 8 + c) * 512 + ig];
        si_s[t] = 1.f / sts[(b * 8 + c) * 512 + ig];
        mi_s[t] = (mask[b * 512 + ig] != 0) ? 1.f : 0.f;
      }
      __syncthreads();
      f32x4 acc[4] = ACC_INIT;
      for (int ks = 0; ks < 2; ks++) {
        bf16x8 ah = frag64(as_[0], w * 16, ks, lane);
        bf16x8 al = frag64(as_[1], w * 16, ks, lane);
#pragma unroll
        for (int nt = 0; nt < 4; nt++)
          mfma3(acc[nt], ah, al, frag64(tsx[0], nt * 16, ks, lane),
                frag64(tsx[1], nt * 16, ks, lane));
      }
      __syncthreads();
#pragma unroll
      for (int nt = 0; nt < 4; nt++) {
        int col = nt * 16 + cl;
        int ig = ii * 64 + col;
        float m_ = sm_s[col], is_ = si_s[col], mi = mi_s[col];
#pragma unroll
        for (int r = 0; r < 4; r++) {
          int row = w * 16 + g * 4 + r;
          int jg = jt * 64 + row;
          bool keep = (kk == 0) ? (jg > ig) : (jg < ig);
          float q = keep ? __expf(acc[nt][r] - m_) * is_ * mi * mjrow[r] : 0.f;
          u16 h, l;
          split2(q, h, l);
          int byte = (row * 128 + col * 2) ^ ((row & 7) << 4);
          *(u16*)((char*)tsx[0] + byte) = h;
          *(u16*)((char*)tsx[1] + byte) = l;
        }
      }
      __syncthreads();
      for (int ks = 0; ks < 2; ks++) {
        bf16x8 ah = frag64(tsx[0], w * 16, ks, lane);
        bf16x8 al = frag64(tsx[1], w * 16, ks, lane);
#pragma unroll
        for (int nt = 0; nt < 4; nt++)
          mfma3(accA[kk][nt], ah, al, frag64(bt[0], nt * 16, ks, lane),
                frag64(bt[1], nt * 16, ks, lane));
      }
    }
  }
#pragma unroll
  for (int kk = 0; kk < 2; kk++)
#pragma unroll
    for (int nt = 0; nt < 4; nt++)
#pragma unroll
      for (int r = 0; r < 4; r++) {
        size_t o = ((size_t)b * 512 + jt * 64 + w * 16 + g * 4 + r) * 1024 +
                   kk * 512 + c * 64 + nt * 16 + cl;
        u16 h, l;
        split2(accA[kk][nt][r], h, l);
        A2h[o] = h;
        A2l[o] = l;
      }
}

// ---------------------------------------------------------------------------
// F[b][m][n] = sum_{K=1024} A[b][m][K]·Tp[n][K]  (split in, fp32 out)
// ---------------------------------------------------------------------------
__global__ __launch_bounds__(256) void mm_fz_kernel(
    const u16* __restrict__ Ah, const u16* __restrict__ Al,
    const u16* __restrict__ Bh, const u16* __restrict__ Bl,
    float* __restrict__ F) {
  int blk = blockIdx.x;  // b*8 + it
  int it = blk & 7, b = blk >> 3;
  __shared__ u16 ah_s[4096], al_s[4096], bh_s[4096], bl_s[4096];
  int t = threadIdx.x, lane = t & 63, w = t >> 6;
  f32x4 acc[4] = ACC_INIT;
  size_t abase = ((size_t)b * 512 + it * 64) * 1024;
  for (int ch = 0; ch < 16; ch++) {
    __syncthreads();
    stage64(ah_s, Ah + abase + ch * 64, 1024, t);
    stage64(al_s, Al + abase + ch * 64, 1024, t);
    stage64(bh_s, Bh + ch * 64, 1024, t);
    stage64(bl_s, Bl + ch * 64, 1024, t);
    __syncthreads();
    for (int ks = 0; ks < 2; ks++) {
      bf16x8 ah = frag64(ah_s, w * 16, ks, lane);
      bf16x8 al = frag64(al_s, w * 16, ks, lane);
#pragma unroll
      for (int nt = 0; nt < 4; nt++)
        mfma3(acc[nt], ah, al, frag64(bh_s, nt * 16, ks, lane),
              frag64(bl_s, nt * 16, ks, lane));
    }
  }
  int rb = (lane >> 4) * 4, cl = lane & 15;
#pragma unroll
  for (int nt = 0; nt < 4; nt++)
#pragma unroll
    for (int r = 0; r < 4; r++)
      F[((size_t)b * 512 + it * 64 + w * 16 + rb + r) * 64 + nt * 16 + cl] =
          acc[nt][r];
}

// ---------------------------------------------------------------------------
// q_g[b,i,g] = softmax_g( sum_a q_z[b,i,a]*gw[g,a] ) * m1   (fp32)
// ---------------------------------------------------------------------------
__global__ __launch_bounds__(256) void qg_kernel(
    const float* __restrict__ q_z, const float* __restrict__ gw,
    const int* __restrict__ mask, float* __restrict__ q_g) {
  int blk = blockIdx.x;
  int ic = blk & 15, b = blk >> 4;
  __shared__ float gw_s[64][65];
  __shared__ float qz_s[32][64];
  __shared__ float fg_s[32][65];
  int t = threadIdx.x;
  for (int p = t; p < 4096; p += 256) {
    int g = p >> 6, a = p & 63;
    gw_s[g][a] = gw[g * 64 + a];
  }
  int i0 = ic * 32;
  for (int p = t; p < 2048; p += 256) {
    int il = p >> 6, a = p & 63;
    qz_s[il][a] = q_z[(b * LL + i0 + il) * 64 + a];
  }
  __syncthreads();
  int g = t & 63, il0 = t >> 6;
#pragma unroll
  for (int s = 0; s < 8; s++) {
    int il = il0 + 4 * s;
    float acc = 0.f;
    for (int a = 0; a < 64; a++) acc += qz_s[il][a] * gw_s[g][a];
    fg_s[il][g] = acc;
  }
  __syncthreads();
  if (t < 32) {
    float m = -1e30f;
    for (int g2 = 0; g2 < 64; g2++) m = fmaxf(m, fg_s[t][g2]);
    float s = 0.f;
    for (int g2 = 0; g2 < 64; g2++) {
      float e = __expf(fg_s[t][g2] - m);
      fg_s[t][g2] = e;
      s += e;
    }
    float mi = (mask[b * LL + i0 + t] != 0) ? 1.f : 0.f;
    float inv = mi / s;
    for (int g2 = 0; g2 < 64; g2++)
      q_g[(b * LL + i0 + t) * 64 + g2] = fg_s[t][g2] * inv;
  }
}

// ---------------------------------------------------------------------------
// Q_Z_new = x + F1 + F2 + q_g @ gw
// ---------------------------------------------------------------------------
__global__ __launch_bounds__(256) void fz_kernel(
    const float* __restrict__ x, const float* __restrict__ F1,
    const float* __restrict__ F2, const float* __restrict__ q_g,
    const float* __restrict__ gw, float* __restrict__ out) {
  int blk = blockIdx.x;
  int ic = blk & 15, b = blk >> 4;
  int i0 = ic * 32;
  int t = threadIdx.x;
  __shared__ float gw_s[64][65];
  __shared__ float qg_s[32][64];
  for (int p = t; p < 4096; p += 256) {
    int g = p >> 6, a = p & 63;
    gw_s[g][a] = gw[g * 64 + a];
  }
  for (int p = t; p < 2048; p += 256) {
    int il = p >> 6, g = p & 63;
    qg_s[il][g] = q_g[(b * LL + i0 + il) * 64 + g];
  }
  __syncthreads();
  int a = t & 63, il0 = t >> 6;
#pragma unroll
  for (int s = 0; s < 8; s++) {
    int il = il0 + 4 * s;
    float acc = 0.f;
    for (int g = 0; g < 64; g++) acc += qg_s[il][g] * gw_s[g][a];
    size_t idx = (size_t)(b * LL + i0 + il) * 64 + a;
    out[idx] = x[idx] + F1[idx] + F2[idx] + acc;
  }
}

// ---------------------------------------------------------------------------
extern "C" void kernel_launch(void* const* d_in, const int* in_sizes, int n_in,
                              void* d_out, int out_size, void* d_ws,
                              size_t ws_size, hipStream_t stream) {
  const float* x = (const float*)d_in[0];
  const int* mask = (const int*)d_in[1];
  const float* ternary = (const float*)d_in[2];
  const float* gw = (const float*)d_in[3];
  float* out = (float*)d_out;

  char* w = (char*)d_ws;
  float* qz_f = (float*)(w);                          // 1 MB
  float* Q_Z = (float*)(w + (1 << 20));               // 1 MB
  float* q_g = (float*)(w + (2 << 20));               // 1 MB
  float* F1 = (float*)(w + (3 << 20));                // 1 MB
  float* F2 = (float*)(w + (4 << 20));                // 1 MB
  u16* qzh = (u16*)(w + (5 << 20));                   // 512 KB
  u16* qzl = (u16*)(w + (5 << 20) + (512 << 10));     // 512 KB
  u16* qzTh = (u16*)(w + (6 << 20));                  // 512 KB
  u16* qzTl = (u16*)(w + (6 << 20) + (512 << 10));    // 512 KB
  u16* TBh = (u16*)(w + (7 << 20));                   // 6 x 128 KB
  u16* TBl = (u16*)(w + (7 << 20) + (128 << 10));
  u16* T1ph = (u16*)(w + (7 << 20) + (256 << 10));
  u16* T1pl = (u16*)(w + (7 << 20) + (384 << 10));
  u16* T2ph = (u16*)(w + (7 << 20) + (512 << 10));
  u16* T2pl = (u16*)(w + (7 << 20) + (640 << 10));
  float* stm = (float*)(w + (8 << 20));               // 128 KB
  float* sts = (float*)(w + (8 << 20) + (128 << 10)); // 128 KB
  u16* t1h = (u16*)(w + (9 << 20));                   // 8 MB
  u16* t1l = (u16*)(w + (17 << 20));                  // 8 MB
  u16* A1h = (u16*)(w + (25 << 20));                  // 8 MB
  u16* A1l = (u16*)(w + (33 << 20));                  // 8 MB
  u16* A2h = (u16*)(w + (41 << 20));                  // 8 MB
  u16* A2l = (u16*)(w + (49 << 20));                  // 8 MB -> 57 MB total

  repack_kernel<<<256, 256, 0, stream>>>(ternary, TBh, TBl, T1ph, T1pl, T2ph,
                                         T2pl);
  const float* zin = x;
  for (int iter = 0; iter < NITER; iter++) {
    softmax_z_kernel<<<BB * LL, 64, 0, stream>>>(zin, mask, qz_f, qzh, qzl);
    qzT_kernel<<<128, 256, 0, stream>>>(qzh, qzl, qzTh, qzTl);
    mm_t1_kernel<<<1024, 256, 0, stream>>>(qzh, qzl, TBh, TBl, t1h, t1l);
    stats_kernel<<<512, 256, 0, stream>>>(t1h, t1l, qzh, qzl, stm, sts);
    a1_kernel<<<512, 256, 0, stream>>>(t1h, t1l, qzh, qzl, qzTh, qzTl, stm,
                                       sts, mask, A1h, A1l);
    a2_kernel<<<512, 256, 0, stream>>>(t1h, t1l, qzh, qzl, qzTh, qzTl, stm,
                                       sts, mask, A2h, A2l);
    mm_fz_kernel<<<64, 256, 0, stream>>>(A1h, A1l, T1ph, T1pl, F1);
    mm_fz_kernel<<<64, 256, 0, stream>>>(A2h, A2l, T2ph, T2pl, F2);
    qg_kernel<<<128, 256, 0, stream>>>(qz_f, gw, mask, q_g);
    float* zout = (iter == NITER - 1) ? out : Q_Z;
    fz_kernel<<<128, 256, 0, stream>>>(x, F1, F2, q_g, gw, zout);
    zin = Q_Z;
  }
}

// Round 4
// 444.198 us; speedup vs baseline: 8.2680x; 1.7871x over previous
//
#include <hip/hip_runtime.h>
#include <hip/hip_bf16.h>

#define BB 8
#define LL 512
#define CC 8
#define NITER 3
#define NP 8  // split-K parts for mm_fz

typedef __attribute__((ext_vector_type(8))) short bf16x8;
typedef __attribute__((ext_vector_type(4))) float f32x4;
typedef unsigned short u16;

__device__ inline u16 f2b(float f) {
  __hip_bfloat16 h = __float2bfloat16(f);
  return *reinterpret_cast<u16*>(&h);
}
__device__ inline float b2f(u16 u) {
  __hip_bfloat16 h;
  *reinterpret_cast<u16*>(&h) = u;
  return __bfloat162float(h);
}
__device__ inline void split2(float v, u16& hi, u16& lo) {
  hi = f2b(v);
  lo = f2b(v - b2f(hi));
}

// Stage a [64][64] bf16 tile (row stride ld) into LDS, XOR-swizzled.
__device__ inline void stageT(u16* lds, const u16* __restrict__ src, int ld,
                              int t, int nthr) {
  for (int ch = t; ch < 512; ch += nthr) {
    int r = ch >> 3, seg = ch & 7;
    int byte = (r * 128 + seg * 16) ^ ((r & 7) << 4);
    *(bf16x8*)((char*)lds + byte) = *(const bf16x8*)(src + r * ld + seg * 8);
  }
}
// mfma_16x16x32 operand fragment from swizzled tile: rows row0..row0+15.
__device__ inline bf16x8 frag64(const u16* lds, int row0, int ks, int lane) {
  int r = row0 + (lane & 15);
  int byte = (r * 128 + ks * 64 + ((lane >> 4) << 4)) ^ ((r & 7) << 4);
  return *(const bf16x8*)((const char*)lds + byte);
}
// split-precision accumulate: acc += Ah*Bh + Ah*Bl + Al*Bh
__device__ inline void mfma3(f32x4& acc, bf16x8 ah, bf16x8 al, bf16x8 bh,
                             bf16x8 bl) {
  acc = __builtin_amdgcn_mfma_f32_16x16x32_bf16(ah, bh, acc, 0, 0, 0);
  acc = __builtin_amdgcn_mfma_f32_16x16x32_bf16(ah, bl, acc, 0, 0, 0);
  acc = __builtin_amdgcn_mfma_f32_16x16x32_bf16(al, bh, acc, 0, 0, 0);
}

#define ACC_INIT {{0.f,0.f,0.f,0.f},{0.f,0.f,0.f,0.f},{0.f,0.f,0.f,0.f},{0.f,0.f,0.f,0.f}}

// ---------------------------------------------------------------------------
// repack ternary to split pairs: TB[k,c][e][a], T1p[a][k,c,e], T2p[e][k,c,a]
// ---------------------------------------------------------------------------
__global__ __launch_bounds__(256) void repack_kernel(
    const float* __restrict__ T, u16* TBh, u16* TBl, u16* T1h, u16* T1l,
    u16* T2h, u16* T2l) {
  int tid = blockIdx.x * 256 + threadIdx.x;  // [2][64][64][8]
  int c = tid & 7, e = (tid >> 3) & 63, a = (tid >> 9) & 63, kk = tid >> 15;
  u16 hi, lo;
  split2(T[tid], hi, lo);
  int iTB = ((kk * 8 + c) * 64 + e) * 64 + a;
  int i1 = a * 1024 + kk * 512 + c * 64 + e;
  int i2 = e * 1024 + kk * 512 + c * 64 + a;
  TBh[iTB] = hi; TBl[iTB] = lo;
  T1h[i1] = hi;  T1l[i1] = lo;
  T2h[i2] = hi;  T2l[i2] = lo;
}

// ---------------------------------------------------------------------------
// q_z = softmax(Q_Z) * m1 ; fp32 + split-bf16 copies
// ---------------------------------------------------------------------------
__global__ __launch_bounds__(64) void softmax_z_kernel(
    const float* __restrict__ in, const int* __restrict__ mask,
    float* __restrict__ qz, u16* __restrict__ qzh, u16* __restrict__ qzl) {
  int row = blockIdx.x;
  int t = threadIdx.x;
  float v = in[row * 64 + t];
  float m = v;
  for (int o = 32; o; o >>= 1) m = fmaxf(m, __shfl_xor(m, o));
  float e = __expf(v - m);
  float s = e;
  for (int o = 32; o; o >>= 1) s += __shfl_xor(s, o);
  float mi = (mask[row] != 0) ? 1.f : 0.f;
  float r = e / s * mi;
  qz[row * 64 + t] = r;
  u16 hi, lo;
  split2(r, hi, lo);
  qzh[row * 64 + t] = hi;
  qzl[row * 64 + t] = lo;
}

// qzT[b][a][i] = qz[b][i][a]  (hi and lo)
__global__ __launch_bounds__(256) void qzT_kernel(
    const u16* __restrict__ qzh, const u16* __restrict__ qzl,
    u16* __restrict__ qzTh, u16* __restrict__ qzTl) {
  int blk = blockIdx.x;  // sel*64 + b*8 + it
  int it = blk & 7, b = (blk >> 3) & 7, sel = blk >> 6;
  const u16* src = sel ? qzl : qzh;
  u16* dst = sel ? qzTl : qzTh;
  __shared__ u16 s[64][65];
  int t = threadIdx.x;
  for (int p = t; p < 4096; p += 256) {
    int r = p >> 6, a = p & 63;
    s[r][a] = src[(b * 512 + it * 64 + r) * 64 + a];
  }
  __syncthreads();
  for (int p = t; p < 4096; p += 256) {
    int a = p >> 6, i = p & 63;
    dst[(b * 64 + a) * 512 + it * 64 + i] = s[i][a];
  }
}

// ---------------------------------------------------------------------------
// t1[kk,b,c][i][e] = sum_a qz[b,i,a] * T[kk,a,e,c]   (split out)
// ---------------------------------------------------------------------------
__global__ __launch_bounds__(256) void mm_t1_kernel(
    const u16* __restrict__ qzh, const u16* __restrict__ qzl,
    const u16* __restrict__ TBh, const u16* __restrict__ TBl,
    u16* __restrict__ t1h, u16* __restrict__ t1l) {
  int blk = blockIdx.x;  // kk*512 + b*64 + c*8 + it
  int it = blk & 7, c = (blk >> 3) & 7, b = (blk >> 6) & 7, kk = blk >> 9;
  __shared__ u16 ah_s[4096], al_s[4096], bh_s[4096], bl_s[4096];
  int t = threadIdx.x, lane = t & 63, w = t >> 6;
  stageT(ah_s, qzh + (b * 512 + it * 64) * 64, 64, t, 256);
  stageT(al_s, qzl + (b * 512 + it * 64) * 64, 64, t, 256);
  stageT(bh_s, TBh + (kk * 8 + c) * 4096, 64, t, 256);
  stageT(bl_s, TBl + (kk * 8 + c) * 4096, 64, t, 256);
  __syncthreads();
  f32x4 acc[4] = ACC_INIT;
  for (int ks = 0; ks < 2; ks++) {
    bf16x8 ah = frag64(ah_s, w * 16, ks, lane);
    bf16x8 al = frag64(al_s, w * 16, ks, lane);
#pragma unroll
    for (int nt = 0; nt < 4; nt++)
      mfma3(acc[nt], ah, al, frag64(bh_s, nt * 16, ks, lane),
            frag64(bl_s, nt * 16, ks, lane));
  }
  size_t base = ((size_t)((kk * 8 + b) * 8 + c)) * 32768;
  int rb = (lane >> 4) * 4, cl = lane & 15;
#pragma unroll
  for (int nt = 0; nt < 4; nt++)
#pragma unroll
    for (int r = 0; r < 4; r++) {
      size_t o = base + (size_t)(it * 64 + w * 16 + rb + r) * 64 + nt * 16 + cl;
      u16 h, l;
      split2(acc[nt][r], h, l);
      t1h[o] = h;
      t1l[o] = l;
    }
}

// ---------------------------------------------------------------------------
// a1: fused online-softmax + A1 = (qh*dm) @ qz.  Writes stm/sts for a2.
// 512 threads: wave w -> row-group rg=w&3 (16 rows), col-half nh=w>>2.
// ---------------------------------------------------------------------------
__global__ __launch_bounds__(512, 4) void a1_kernel(
    const u16* __restrict__ t1h, const u16* __restrict__ t1l,
    const u16* __restrict__ qzh, const u16* __restrict__ qzl,
    const u16* __restrict__ qzTh, const u16* __restrict__ qzTl,
    const int* __restrict__ mask, float* __restrict__ stm,
    float* __restrict__ sts, u16* __restrict__ A1h, u16* __restrict__ A1l) {
  int blk = blockIdx.x;  // b*64 + c*8 + it
  int it = blk & 7, c = (blk >> 3) & 7, b = blk >> 6;
  __shared__ u16 ts2[2][2][4096];  // [kk][hl] t1 tiles, staged once
  __shared__ u16 bx[2][4096];      // qz[jt] -> qh overlay
  __shared__ u16 bt[2][4096];      // qzT j-chunk
  __shared__ float pm[2][64], ps[2][64];
  int t = threadIdx.x, lane = t & 63, w = t >> 6, cl = lane & 15, g = lane >> 4;
  int rg = w & 3, nh = w >> 2;
  const size_t KSTR = (size_t)64 * 32768;
  size_t tb = ((size_t)(b * 8 + c)) * 32768 + it * 4096;
  stageT(ts2[0][0], t1h + tb, 64, t, 512);
  stageT(ts2[0][1], t1l + tb, 64, t, 512);
  stageT(ts2[1][0], t1h + tb + KSTR, 64, t, 512);
  stageT(ts2[1][1], t1l + tb + KSTR, 64, t, 512);
  float mi_[4], m_run[4], s_run[4];
#pragma unroll
  for (int r = 0; r < 4; r++) {
    int ig = it * 64 + rg * 16 + g * 4 + r;
    mi_[r] = (mask[b * 512 + ig] != 0) ? 1.f : 0.f;
    m_run[r] = -3.0e38f;
    s_run[r] = 0.f;
  }
  f32x4 accA[2][2];
#pragma unroll
  for (int kk = 0; kk < 2; kk++)
#pragma unroll
    for (int ntl = 0; ntl < 2; ntl++) accA[kk][ntl] = (f32x4){0.f, 0.f, 0.f, 0.f};

  for (int jt = 0; jt < 8; jt++) {
    int diag = (jt == it);
    int npass = diag ? 2 : 1;
    int k0 = (jt > it) ? 0 : 1;
    for (int p = 0; p < npass; p++) {
      int kk = diag ? p : k0;
      __syncthreads();  // protect bx/bt/pm/ps overwrite vs prev GEMM2 reads
      stageT(bx[0], qzh + (b * 512 + jt * 64) * 64, 64, t, 512);
      stageT(bx[1], qzl + (b * 512 + jt * 64) * 64, 64, t, 512);
      if (p == 0) {
        stageT(bt[0], qzTh + (size_t)b * 32768 + jt * 64, 512, t, 512);
        stageT(bt[1], qzTl + (size_t)b * 32768 + jt * 64, 512, t, 512);
      }
      __syncthreads();
      // GEMM1: logits L[i][j] for this wave's quarter
      f32x4 acc[2] = {{0.f, 0.f, 0.f, 0.f}, {0.f, 0.f, 0.f, 0.f}};
      for (int ks = 0; ks < 2; ks++) {
        bf16x8 ah = frag64(ts2[kk][0], rg * 16, ks, lane);
        bf16x8 al = frag64(ts2[kk][1], rg * 16, ks, lane);
#pragma unroll
        for (int ntl = 0; ntl < 2; ntl++) {
          int nt = nh * 2 + ntl;
          mfma3(acc[ntl], ah, al, frag64(bx[0], nt * 16, ks, lane),
                frag64(bx[1], nt * 16, ks, lane));
        }
      }
      // per-element valid logits (diag element 0 counted once, in pass 0)
      float Lv[2][4];
#pragma unroll
      for (int ntl = 0; ntl < 2; ntl++) {
        int jg = jt * 64 + (nh * 2 + ntl) * 16 + cl;
#pragma unroll
        for (int r = 0; r < 4; r++) {
          int ig = it * 64 + rg * 16 + g * 4 + r;
          float v;
          if (kk == 0)
            v = (jg > ig) ? acc[ntl][r]
                          : ((diag && p == 0 && jg == ig) ? 0.f : -3.0e38f);
          else
            v = (jg < ig) ? acc[ntl][r] : -3.0e38f;
          Lv[ntl][r] = v;
        }
      }
      // per-wave partial (max, sum)
      float lm[4], lsum[4];
#pragma unroll
      for (int r = 0; r < 4; r++) {
        float m2_ = fmaxf(Lv[0][r], Lv[1][r]);
        for (int o = 1; o < 16; o <<= 1) m2_ = fmaxf(m2_, __shfl_xor(m2_, o));
        float s2_ = __expf(Lv[0][r] - m2_) + __expf(Lv[1][r] - m2_);
        if (m2_ < -1.0e37f) s2_ = 0.f;  // fully-invalid group
        for (int o = 1; o < 16; o <<= 1) s2_ += __shfl_xor(s2_, o);
        lm[r] = m2_;
        lsum[r] = s2_;
      }
      if (cl == 0) {
#pragma unroll
        for (int r = 0; r < 4; r++) {
          pm[nh][rg * 16 + g * 4 + r] = lm[r];
          ps[nh][rg * 16 + g * 4 + r] = lsum[r];
        }
      }
      __syncthreads();  // GEMM1 bx reads done + pm/ps visible
      // combine halves, update running (m,s), rescale accA
#pragma unroll
      for (int r = 0; r < 4; r++) {
        int row = rg * 16 + g * 4 + r;
        float m0 = pm[0][row], m1 = pm[1][row];
        float tm = fmaxf(m0, m1);
        float tsum = ps[0][row] * __expf(m0 - tm) + ps[1][row] * __expf(m1 - tm);
        float mn = fmaxf(m_run[r], tm);
        float sc = __expf(m_run[r] - mn);
        s_run[r] = s_run[r] * sc + tsum * __expf(tm - mn);
        m_run[r] = mn;
#pragma unroll
        for (int kk2 = 0; kk2 < 2; kk2++)
#pragma unroll
          for (int ntl = 0; ntl < 2; ntl++) accA[kk2][ntl][r] *= sc;
      }
      // write qh (unnormalized, col-masked, strict triangle) into bx overlay
#pragma unroll
      for (int ntl = 0; ntl < 2; ntl++) {
        int col = (nh * 2 + ntl) * 16 + cl;
        int jg = jt * 64 + col;
        float mj = (mask[b * 512 + jg] != 0) ? 1.f : 0.f;
#pragma unroll
        for (int r = 0; r < 4; r++) {
          int row = rg * 16 + g * 4 + r;
          int ig = it * 64 + row;
          bool keep = (kk == 0) ? (jg > ig) : (jg < ig);
          float q = keep ? __expf(Lv[ntl][r] - m_run[r]) * mj : 0.f;
          u16 h, l;
          split2(q, h, l);
          int byte = (row * 128 + col * 2) ^ ((row & 7) << 4);
          *(u16*)((char*)bx[0] + byte) = h;
          *(u16*)((char*)bx[1] + byte) = l;
        }
      }
      __syncthreads();
      // GEMM2: accA[kk] += qh @ qzT
      for (int ks = 0; ks < 2; ks++) {
        bf16x8 ah = frag64(bx[0], rg * 16, ks, lane);
        bf16x8 al = frag64(bx[1], rg * 16, ks, lane);
#pragma unroll
        for (int ntl = 0; ntl < 2; ntl++) {
          int nt = nh * 2 + ntl;
          mfma3(accA[kk][ntl], ah, al, frag64(bt[0], nt * 16, ks, lane),
                frag64(bt[1], nt * 16, ks, lane));
        }
      }
    }
  }
  // epilogue: apply row scale mi/s
#pragma unroll
  for (int r = 0; r < 4; r++) {
    float sfin = mi_[r] / s_run[r];
    int row = it * 64 + rg * 16 + g * 4 + r;
#pragma unroll
    for (int kk = 0; kk < 2; kk++)
#pragma unroll
      for (int ntl = 0; ntl < 2; ntl++) {
        size_t o = ((size_t)b * 512 + row) * 1024 + kk * 512 + c * 64 +
                   (nh * 2 + ntl) * 16 + cl;
        u16 h, l;
        split2(accA[kk][ntl][r] * sfin, h, l);
        A1h[o] = h;
        A1l[o] = l;
      }
  }
  if (nh == 0 && cl == 0) {
#pragma unroll
    for (int r = 0; r < 4; r++) {
      int i = it * 64 + rg * 16 + g * 4 + r;
      stm[(b * 8 + c) * 512 + i] = m_run[r];
      sts[(b * 8 + c) * 512 + i] = s_run[r];
    }
  }
}

// ---------------------------------------------------------------------------
// a2: A2[b][j][kk,c,a] = sum_i qh[kk][i][j]·qz[i][a]  (recompute, uses stats)
// ---------------------------------------------------------------------------
__global__ __launch_bounds__(512, 4) void a2_kernel(
    const u16* __restrict__ t1h, const u16* __restrict__ t1l,
    const u16* __restrict__ qzh, const u16* __restrict__ qzl,
    const u16* __restrict__ qzTh, const u16* __restrict__ qzTl,
    const float* __restrict__ stm, const float* __restrict__ sts,
    const int* __restrict__ mask, u16* __restrict__ A2h,
    u16* __restrict__ A2l) {
  int blk = blockIdx.x;  // b*64 + c*8 + jt
  int jt = blk & 7, c = (blk >> 3) & 7, b = blk >> 6;
  __shared__ u16 as_[2][4096];  // qz[jt] (logit A operand)
  __shared__ u16 tsx[2][4096];  // t1[ii][kk] -> qhT overlay
  __shared__ u16 bt[2][4096];   // qzT i-chunk
  __shared__ float sm_s[64], si_s[64], mi_s[64];
  int t = threadIdx.x, lane = t & 63, w = t >> 6, cl = lane & 15, g = lane >> 4;
  int rg = w & 3, nh = w >> 2;
  const size_t KSTR = (size_t)64 * 32768;
  size_t tbb = ((size_t)(b * 8 + c)) * 32768;
  stageT(as_[0], qzh + (b * 512 + jt * 64) * 64, 64, t, 512);
  stageT(as_[1], qzl + (b * 512 + jt * 64) * 64, 64, t, 512);
  float mjrow[4];
#pragma unroll
  for (int r = 0; r < 4; r++) {
    int jg = jt * 64 + rg * 16 + g * 4 + r;
    mjrow[r] = (mask[b * 512 + jg] != 0) ? 1.f : 0.f;
  }
  f32x4 accA[2][2];
#pragma unroll
  for (int kk = 0; kk < 2; kk++)
#pragma unroll
    for (int ntl = 0; ntl < 2; ntl++) accA[kk][ntl] = (f32x4){0.f, 0.f, 0.f, 0.f};

  for (int ii = 0; ii < 8; ii++) {
    int diag = (ii == jt);
    int npass = diag ? 2 : 1;
    int k0 = (ii < jt) ? 0 : 1;
    for (int p = 0; p < npass; p++) {
      int kk = diag ? p : k0;
      __syncthreads();
      stageT(tsx[0], t1h + tbb + ii * 4096 + (size_t)kk * KSTR, 64, t, 512);
      stageT(tsx[1], t1l + tbb + ii * 4096 + (size_t)kk * KSTR, 64, t, 512);
      if (p == 0) {
        stageT(bt[0], qzTh + (size_t)b * 32768 + ii * 64, 512, t, 512);
        stageT(bt[1], qzTl + (size_t)b * 32768 + ii * 64, 512, t, 512);
        if (t < 64) {
          int ig = ii * 64 + t;
          sm_s[t] = stm[(b * 8 + c) * 512 + ig];
          si_s[t] = 1.f / sts[(b * 8 + c) * 512 + ig];
          mi_s[t] = (mask[b * 512 + ig] != 0) ? 1.f : 0.f;
        }
      }
      __syncthreads();
      // GEMM1: LT[j][i] = qz[j]·t1[i]
      f32x4 acc[2] = {{0.f, 0.f, 0.f, 0.f}, {0.f, 0.f, 0.f, 0.f}};
      for (int ks = 0; ks < 2; ks++) {
        bf16x8 ah = frag64(as_[0], rg * 16, ks, lane);
        bf16x8 al = frag64(as_[1], rg * 16, ks, lane);
#pragma unroll
        for (int ntl = 0; ntl < 2; ntl++) {
          int nt = nh * 2 + ntl;
          mfma3(acc[ntl], ah, al, frag64(tsx[0], nt * 16, ks, lane),
                frag64(tsx[1], nt * 16, ks, lane));
        }
      }
      __syncthreads();  // tsx GEMM1 reads done before overlay
      // qh^T write into tsx overlay (full normalization per col i)
#pragma unroll
      for (int ntl = 0; ntl < 2; ntl++) {
        int col = (nh * 2 + ntl) * 16 + cl;
        int ig = ii * 64 + col;
        float m_ = sm_s[col], is_ = si_s[col], mi = mi_s[col];
#pragma unroll
        for (int r = 0; r < 4; r++) {
          int row = rg * 16 + g * 4 + r;
          int jg = jt * 64 + row;
          bool keep = (kk == 0) ? (jg > ig) : (jg < ig);
          float q = keep ? __expf(acc[ntl][r] - m_) * is_ * mi * mjrow[r] : 0.f;
          u16 h, l;
          split2(q, h, l);
          int byte = (row * 128 + col * 2) ^ ((row & 7) << 4);
          *(u16*)((char*)tsx[0] + byte) = h;
          *(u16*)((char*)tsx[1] + byte) = l;
        }
      }
      __syncthreads();
      // GEMM2: accA[kk] += qhT @ qzT
      for (int ks = 0; ks < 2; ks++) {
        bf16x8 ah = frag64(tsx[0], rg * 16, ks, lane);
        bf16x8 al = frag64(tsx[1], rg * 16, ks, lane);
#pragma unroll
        for (int ntl = 0; ntl < 2; ntl++) {
          int nt = nh * 2 + ntl;
          mfma3(accA[kk][ntl], ah, al, frag64(bt[0], nt * 16, ks, lane),
                frag64(bt[1], nt * 16, ks, lane));
        }
      }
    }
  }
#pragma unroll
  for (int r = 0; r < 4; r++) {
    int row = jt * 64 + rg * 16 + g * 4 + r;
#pragma unroll
    for (int kk = 0; kk < 2; kk++)
#pragma unroll
      for (int ntl = 0; ntl < 2; ntl++) {
        size_t o = ((size_t)b * 512 + row) * 1024 + kk * 512 + c * 64 +
                   (nh * 2 + ntl) * 16 + cl;
        u16 h, l;
        split2(accA[kk][ntl][r], h, l);
        A2h[o] = h;
        A2l[o] = l;
      }
  }
}

// ---------------------------------------------------------------------------
// F{1,2} partials: Fp[part][b][m][n] = sum_{K part} A[b][m][K]·Tp[n][K]
// blk = sel*512 + part*64 + b*8 + it  (sel: 0->F1, 1->F2)
// ---------------------------------------------------------------------------
__global__ __launch_bounds__(256) void mm_fz_kernel(
    const u16* __restrict__ A1h, const u16* __restrict__ A1l,
    const u16* __restrict__ A2h, const u16* __restrict__ A2l,
    const u16* __restrict__ T1ph, const u16* __restrict__ T1pl,
    const u16* __restrict__ T2ph, const u16* __restrict__ T2pl,
    float* __restrict__ F1p, float* __restrict__ F2p) {
  int blk = blockIdx.x;
  int it = blk & 7, b = (blk >> 3) & 7, part = (blk >> 6) & 7, sel = blk >> 9;
  const u16* Ah = sel ? A2h : A1h;
  const u16* Al = sel ? A2l : A1l;
  const u16* Bh = sel ? T2ph : T1ph;
  const u16* Bl = sel ? T2pl : T1pl;
  float* Fp = (sel ? F2p : F1p) + (size_t)part * (BB * 512 * 64);
  __shared__ u16 ah_s[4096], al_s[4096], bh_s[4096], bl_s[4096];
  int t = threadIdx.x, lane = t & 63, w = t >> 6;
  f32x4 acc[4] = ACC_INIT;
  size_t abase = ((size_t)b * 512 + it * 64) * 1024;
  for (int cc2 = 0; cc2 < 2; cc2++) {
    int ch = part * 2 + cc2;
    __syncthreads();
    stageT(ah_s, Ah + abase + ch * 64, 1024, t, 256);
    stageT(al_s, Al + abase + ch * 64, 1024, t, 256);
    stageT(bh_s, Bh + ch * 64, 1024, t, 256);
    stageT(bl_s, Bl + ch * 64, 1024, t, 256);
    __syncthreads();
    for (int ks = 0; ks < 2; ks++) {
      bf16x8 ah = frag64(ah_s, w * 16, ks, lane);
      bf16x8 al = frag64(al_s, w * 16, ks, lane);
#pragma unroll
      for (int nt = 0; nt < 4; nt++)
        mfma3(acc[nt], ah, al, frag64(bh_s, nt * 16, ks, lane),
              frag64(bl_s, nt * 16, ks, lane));
    }
  }
  int rb = (lane >> 4) * 4, cl = lane & 15;
#pragma unroll
  for (int nt = 0; nt < 4; nt++)
#pragma unroll
    for (int r = 0; r < 4; r++)
      Fp[((size_t)b * 512 + it * 64 + w * 16 + rb + r) * 64 + nt * 16 + cl] =
          acc[nt][r];
}

// ---------------------------------------------------------------------------
// fused q_g + F_Z:  out = x + sum_p F1p + sum_p F2p + softmax(qz@gw^T)*m1 @ gw
// ---------------------------------------------------------------------------
__global__ __launch_bounds__(256) void fzqg_kernel(
    const float* __restrict__ x, const float* __restrict__ F1p,
    const float* __restrict__ F2p, const float* __restrict__ qz,
    const float* __restrict__ gw, const int* __restrict__ mask,
    float* __restrict__ out) {
  int blk = blockIdx.x;
  int ic = blk & 15, b = blk >> 4;
  int i0 = ic * 32;
  int t = threadIdx.x;
  __shared__ float gw_s[64][65];
  __shared__ float qz_s[32][64];
  __shared__ float fg_s[32][65];
  for (int p = t; p < 4096; p += 256) gw_s[p >> 6][p & 63] = gw[p];
  for (int p = t; p < 2048; p += 256) {
    int il = p >> 6, a = p & 63;
    qz_s[il][a] = qz[(b * LL + i0 + il) * 64 + a];
  }
  __syncthreads();
  int gcol = t & 63, il0 = t >> 6;
#pragma unroll
  for (int s = 0; s < 8; s++) {
    int il = il0 + 4 * s;
    float acc = 0.f;
    for (int a = 0; a < 64; a++) acc += qz_s[il][a] * gw_s[gcol][a];
    fg_s[il][gcol] = acc;
  }
  __syncthreads();
  // parallel row softmax: 8 threads per row
  {
    int r = t >> 3, k = t & 7;
    float v[8];
#pragma unroll
    for (int u = 0; u < 8; u++) v[u] = fg_s[r][k * 8 + u];
    float m = v[0];
#pragma unroll
    for (int u = 1; u < 8; u++) m = fmaxf(m, v[u]);
    for (int o = 1; o < 8; o <<= 1) m = fmaxf(m, __shfl_xor(m, o));
    float s = 0.f;
#pragma unroll
    for (int u = 0; u < 8; u++) s += __expf(v[u] - m);
    for (int o = 1; o < 8; o <<= 1) s += __shfl_xor(s, o);
    float mi = (mask[b * LL + i0 + r] != 0) ? 1.f : 0.f;
    float inv = mi / s;
#pragma unroll
    for (int u = 0; u < 8; u++) fg_s[r][k * 8 + u] = __expf(v[u] - m) * inv;
  }
  __syncthreads();
  int a = t & 63;
#pragma unroll
  for (int s = 0; s < 8; s++) {
    int il = il0 + 4 * s;
    float acc = 0.f;
    for (int g2 = 0; g2 < 64; g2++) acc += fg_s[il][g2] * gw_s[g2][a];
    size_t idx = (size_t)(b * LL + i0 + il) * 64 + a;
    float fs = x[idx] + acc;
    for (int p = 0; p < NP; p++)
      fs += F1p[(size_t)p * (BB * 512 * 64) + idx] +
            F2p[(size_t)p * (BB * 512 * 64) + idx];
    out[idx] = fs;
  }
}

// ---------------------------------------------------------------------------
extern "C" void kernel_launch(void* const* d_in, const int* in_sizes, int n_in,
                              void* d_out, int out_size, void* d_ws,
                              size_t ws_size, hipStream_t stream) {
  const float* x = (const float*)d_in[0];
  const int* mask = (const int*)d_in[1];
  const float* ternary = (const float*)d_in[2];
  const float* gw = (const float*)d_in[3];
  float* out = (float*)d_out;

  char* w = (char*)d_ws;
  float* qz_f = (float*)(w);                           // 1 MB
  float* Q_Z = (float*)(w + (1 << 20));                // 1 MB
  u16* qzh = (u16*)(w + (2 << 20));                    // 512 KB
  u16* qzl = (u16*)(w + (2 << 20) + (512 << 10));      // 512 KB
  u16* qzTh = (u16*)(w + (3 << 20));                   // 512 KB
  u16* qzTl = (u16*)(w + (3 << 20) + (512 << 10));     // 512 KB
  u16* TBh = (u16*)(w + (4 << 20));                    // 6 x 128 KB
  u16* TBl = (u16*)(w + (4 << 20) + (128 << 10));
  u16* T1ph = (u16*)(w + (4 << 20) + (256 << 10));
  u16* T1pl = (u16*)(w + (4 << 20) + (384 << 10));
  u16* T2ph = (u16*)(w + (4 << 20) + (512 << 10));
  u16* T2pl = (u16*)(w + (4 << 20) + (640 << 10));
  float* stm = (float*)(w + (5 << 20));                // 128 KB
  float* sts = (float*)(w + (5 << 20) + (256 << 10));  // 128 KB
  float* F1p = (float*)(w + (6 << 20));                // 8 MB
  float* F2p = (float*)(w + (14 << 20));               // 8 MB
  u16* t1h = (u16*)(w + (22 << 20));                   // 8 MB
  u16* t1l = (u16*)(w + (30 << 20));                   // 8 MB
  u16* A1h = (u16*)(w + (38 << 20));                   // 8 MB
  u16* A1l = (u16*)(w + (46 << 20));                   // 8 MB
  u16* A2h = (u16*)(w + (54 << 20));                   // 8 MB
  u16* A2l = (u16*)(w + (62 << 20));                   // 8 MB -> 70 MB total

  repack_kernel<<<256, 256, 0, stream>>>(ternary, TBh, TBl, T1ph, T1pl, T2ph,
                                         T2pl);
  const float* zin = x;
  for (int iter = 0; iter < NITER; iter++) {
    softmax_z_kernel<<<BB * LL, 64, 0, stream>>>(zin, mask, qz_f, qzh, qzl);
    qzT_kernel<<<128, 256, 0, stream>>>(qzh, qzl, qzTh, qzTl);
    mm_t1_kernel<<<1024, 256, 0, stream>>>(qzh, qzl, TBh, TBl, t1h, t1l);
    a1_kernel<<<512, 512, 0, stream>>>(t1h, t1l, qzh, qzl, qzTh, qzTl, mask,
                                       stm, sts, A1h, A1l);
    a2_kernel<<<512, 512, 0, stream>>>(t1h, t1l, qzh, qzl, qzTh, qzTl, stm,
                                       sts, mask, A2h, A2l);
    mm_fz_kernel<<<1024, 256, 0, stream>>>(A1h, A1l, A2h, A2l, T1ph, T1pl,
                                           T2ph, T2pl, F1p, F2p);
    float* zout = (iter == NITER - 1) ? out : Q_Z;
    fzqg_kernel<<<128, 256, 0, stream>>>(x, F1p, F2p, qz_f, gw, mask, zout);
    zin = Q_Z;
  }
}

// Round 5
// 359.472 us; speedup vs baseline: 10.2167x; 1.2357x over previous
//
#include <hip/hip_runtime.h>
#include <hip/hip_bf16.h>

#define BB 8
#define LL 512
#define CC 8
#define NITER 3
#define NP 8  // split-K parts for mm_fz

typedef __attribute__((ext_vector_type(8))) short bf16x8;
typedef __attribute__((ext_vector_type(4))) float f32x4;
typedef unsigned short u16;

#define MFMA(A, B, C) __builtin_amdgcn_mfma_f32_16x16x32_bf16(A, B, C, 0, 0, 0)

__device__ inline u16 f2b(float f) {
  __hip_bfloat16 h = __float2bfloat16(f);
  return *reinterpret_cast<u16*>(&h);
}
__device__ inline float b2f(u16 u) {
  __hip_bfloat16 h;
  *reinterpret_cast<u16*>(&h) = u;
  return __bfloat162float(h);
}
__device__ inline void split2(float v, u16& hi, u16& lo) {
  hi = f2b(v);
  lo = f2b(v - b2f(hi));
}

// Stage a [64][64] bf16 tile (row stride ld) into LDS, XOR-swizzled.
__device__ inline void stageT(u16* lds, const u16* __restrict__ src, int ld,
                              int t, int nthr) {
  for (int ch = t; ch < 512; ch += nthr) {
    int r = ch >> 3, seg = ch & 7;
    int byte = (r * 128 + seg * 16) ^ ((r & 7) << 4);
    *(bf16x8*)((char*)lds + byte) = *(const bf16x8*)(src + r * ld + seg * 8);
  }
}
// mfma_16x16x32 operand fragment from swizzled tile: rows row0..row0+15.
__device__ inline bf16x8 frag64(const u16* lds, int row0, int ks, int lane) {
  int r = row0 + (lane & 15);
  int byte = (r * 128 + ks * 64 + ((lane >> 4) << 4)) ^ ((r & 7) << 4);
  return *(const bf16x8*)((const char*)lds + byte);
}
// split-precision accumulate: acc += Ah*Bh + Ah*Bl + Al*Bh
__device__ inline void mfma3(f32x4& acc, bf16x8 ah, bf16x8 al, bf16x8 bh,
                             bf16x8 bl) {
  acc = MFMA(ah, bh, acc);
  acc = MFMA(ah, bl, acc);
  acc = MFMA(al, bh, acc);
}

#define ACC_INIT {{0.f,0.f,0.f,0.f},{0.f,0.f,0.f,0.f},{0.f,0.f,0.f,0.f},{0.f,0.f,0.f,0.f}}

// ---------------------------------------------------------------------------
// repack ternary to split pairs: TB[k,c][e][a], T1p[a][k,c,e], T2p[e][k,c,a]
// ---------------------------------------------------------------------------
__global__ __launch_bounds__(256) void repack_kernel(
    const float* __restrict__ T, u16* TBh, u16* TBl, u16* T1h, u16* T1l,
    u16* T2h, u16* T2l) {
  int tid = blockIdx.x * 256 + threadIdx.x;  // [2][64][64][8]
  int c = tid & 7, e = (tid >> 3) & 63, a = (tid >> 9) & 63, kk = tid >> 15;
  u16 hi, lo;
  split2(T[tid], hi, lo);
  int iTB = ((kk * 8 + c) * 64 + e) * 64 + a;
  int i1 = a * 1024 + kk * 512 + c * 64 + e;
  int i2 = e * 1024 + kk * 512 + c * 64 + a;
  TBh[iTB] = hi; TBl[iTB] = lo;
  T1h[i1] = hi;  T1l[i1] = lo;
  T2h[i2] = hi;  T2l[i2] = lo;
}

// ---------------------------------------------------------------------------
// q_z = softmax(Q_Z) * m1 ; fp32 + split-bf16 copies
// ---------------------------------------------------------------------------
__global__ __launch_bounds__(64) void softmax_z_kernel(
    const float* __restrict__ in, const int* __restrict__ mask,
    float* __restrict__ qz, u16* __restrict__ qzh, u16* __restrict__ qzl) {
  int row = blockIdx.x;
  int t = threadIdx.x;
  float v = in[row * 64 + t];
  float m = v;
  for (int o = 32; o; o >>= 1) m = fmaxf(m, __shfl_xor(m, o));
  float e = __expf(v - m);
  float s = e;
  for (int o = 32; o; o >>= 1) s += __shfl_xor(s, o);
  float mi = (mask[row] != 0) ? 1.f : 0.f;
  float r = e / s * mi;
  qz[row * 64 + t] = r;
  u16 hi, lo;
  split2(r, hi, lo);
  qzh[row * 64 + t] = hi;
  qzl[row * 64 + t] = lo;
}

// qzT[b][a][i] = qz[b][i][a]  (hi and lo)
__global__ __launch_bounds__(256) void qzT_kernel(
    const u16* __restrict__ qzh, const u16* __restrict__ qzl,
    u16* __restrict__ qzTh, u16* __restrict__ qzTl) {
  int blk = blockIdx.x;  // sel*64 + b*8 + it
  int it = blk & 7, b = (blk >> 3) & 7, sel = blk >> 6;
  const u16* src = sel ? qzl : qzh;
  u16* dst = sel ? qzTl : qzTh;
  __shared__ u16 s[64][65];
  int t = threadIdx.x;
  for (int p = t; p < 4096; p += 256) {
    int r = p >> 6, a = p & 63;
    s[r][a] = src[(b * 512 + it * 64 + r) * 64 + a];
  }
  __syncthreads();
  for (int p = t; p < 4096; p += 256) {
    int a = p >> 6, i = p & 63;
    dst[(b * 64 + a) * 512 + it * 64 + i] = s[i][a];
  }
}

// ---------------------------------------------------------------------------
// t1[kk,b,c][i][e] = sum_a qz[b,i,a] * T[kk,a,e,c]   (split out)
// ---------------------------------------------------------------------------
__global__ __launch_bounds__(256) void mm_t1_kernel(
    const u16* __restrict__ qzh, const u16* __restrict__ qzl,
    const u16* __restrict__ TBh, const u16* __restrict__ TBl,
    u16* __restrict__ t1h, u16* __restrict__ t1l) {
  int blk = blockIdx.x;  // kk*512 + b*64 + c*8 + it
  int it = blk & 7, c = (blk >> 3) & 7, b = (blk >> 6) & 7, kk = blk >> 9;
  __shared__ u16 ah_s[4096], al_s[4096], bh_s[4096], bl_s[4096];
  int t = threadIdx.x, lane = t & 63, w = t >> 6;
  stageT(ah_s, qzh + (b * 512 + it * 64) * 64, 64, t, 256);
  stageT(al_s, qzl + (b * 512 + it * 64) * 64, 64, t, 256);
  stageT(bh_s, TBh + (kk * 8 + c) * 4096, 64, t, 256);
  stageT(bl_s, TBl + (kk * 8 + c) * 4096, 64, t, 256);
  __syncthreads();
  f32x4 acc[4] = ACC_INIT;
  for (int ks = 0; ks < 2; ks++) {
    bf16x8 ah = frag64(ah_s, w * 16, ks, lane);
    bf16x8 al = frag64(al_s, w * 16, ks, lane);
#pragma unroll
    for (int nt = 0; nt < 4; nt++)
      mfma3(acc[nt], ah, al, frag64(bh_s, nt * 16, ks, lane),
            frag64(bl_s, nt * 16, ks, lane));
  }
  size_t base = ((size_t)((kk * 8 + b) * 8 + c)) * 32768;
  int rb = (lane >> 4) * 4, cl = lane & 15;
#pragma unroll
  for (int nt = 0; nt < 4; nt++)
#pragma unroll
    for (int r = 0; r < 4; r++) {
      size_t o = base + (size_t)(it * 64 + w * 16 + rb + r) * 64 + nt * 16 + cl;
      u16 h, l;
      split2(acc[nt][r], h, l);
      t1h[o] = h;
      t1l[o] = l;
    }
}

// ---------------------------------------------------------------------------
// a1: fused no-max softmax + A1 = (qh*dm) @ qz.  Writes sts (denominators).
// 512 threads: wave w -> row-group rg=w&3 (16 rows), col-half nh=w>>2.
// All register arrays compile-time indexed (accU/accL, tf* named).
// ---------------------------------------------------------------------------
#define A1_PASS(TFH, TFL, ACC, KKis0)                                        \
  {                                                                          \
    f32x4 accq0 = {0.f, 0.f, 0.f, 0.f}, accq1 = {0.f, 0.f, 0.f, 0.f};       \
    _Pragma("unroll") for (int ks = 0; ks < 2; ks++) {                       \
      bf16x8 bh0 = frag64(bx0, (nh * 2) * 16, ks, lane);                     \
      bf16x8 bl0 = frag64(bx1, (nh * 2) * 16, ks, lane);                     \
      bf16x8 bh1 = frag64(bx0, (nh * 2 + 1) * 16, ks, lane);                 \
      bf16x8 bl1 = frag64(bx1, (nh * 2 + 1) * 16, ks, lane);                 \
      accq0 = MFMA(TFH[ks], bh0, accq0);                                     \
      accq0 = MFMA(TFH[ks], bl0, accq0);                                     \
      accq0 = MFMA(TFL[ks], bh0, accq0);                                     \
      accq1 = MFMA(TFH[ks], bh1, accq1);                                     \
      accq1 = MFMA(TFH[ks], bl1, accq1);                                     \
      accq1 = MFMA(TFL[ks], bh1, accq1);                                     \
    }                                                                        \
    _Pragma("unroll") for (int ntl = 0; ntl < 2; ntl++) {                    \
      int col = (nh * 2 + ntl) * 16 + cl;                                    \
      int jg = jt * 64 + col;                                                \
      float mj = (mask[b * 512 + jg] != 0) ? 1.f : 0.f;                      \
      _Pragma("unroll") for (int r = 0; r < 4; r++) {                        \
        int row = rg * 16 + g * 4 + r;                                       \
        int ig = it * 64 + row;                                              \
        float e = __expf(ntl ? accq1[r] : accq0[r]);                         \
        float es, q;                                                         \
        if (KKis0) {                                                         \
          es = (jg > ig) ? e : ((jg == ig) ? 1.f : 0.f);                     \
          q = (jg > ig) ? e * mj : 0.f;                                      \
        } else {                                                             \
          es = (jg < ig) ? e : 0.f;                                          \
          q = (jg < ig) ? e * mj : 0.f;                                      \
        }                                                                    \
        s_run[r] += es;                                                      \
        int byte = (row * 128 + col * 2) ^ ((row & 7) << 4);                 \
        *(u16*)((char*)qh_s + byte) = f2b(q);                                \
      }                                                                      \
    }                                                                        \
    __syncthreads();                                                         \
    _Pragma("unroll") for (int ks = 0; ks < 2; ks++) {                       \
      bf16x8 ah = frag64(qh_s, rg * 16, ks, lane);                           \
      _Pragma("unroll") for (int ntl = 0; ntl < 2; ntl++) {                  \
        int nt = nh * 2 + ntl;                                               \
        bf16x8 bh = frag64(bt0, nt * 16, ks, lane);                          \
        bf16x8 bl = frag64(bt1, nt * 16, ks, lane);                          \
        ACC[ntl] = MFMA(ah, bh, ACC[ntl]);                                   \
        ACC[ntl] = MFMA(ah, bl, ACC[ntl]);                                   \
      }                                                                      \
    }                                                                        \
  }

__global__ __launch_bounds__(512, 4) void a1_kernel(
    const u16* __restrict__ t1h, const u16* __restrict__ t1l,
    const u16* __restrict__ qzh, const u16* __restrict__ qzl,
    const u16* __restrict__ qzTh, const u16* __restrict__ qzTl,
    const int* __restrict__ mask, float* __restrict__ sts,
    u16* __restrict__ A1h, u16* __restrict__ A1l) {
  int blk = blockIdx.x;  // b*64 + c*8 + it
  int it = blk & 7, c = (blk >> 3) & 7, b = blk >> 6;
  __shared__ u16 smem[20736];  // 41472 B total
  u16* bx0 = smem;             // qz[jt] hi
  u16* bx1 = smem + 4096;      // qz[jt] lo
  u16* bt0 = smem + 8192;      // qzT hi
  u16* bt1 = smem + 12288;     // qzT lo
  u16* qh_s = smem + 16384;    // qh hi
  float* ps = (float*)(smem + 20480);  // [2][64]
  int t = threadIdx.x, lane = t & 63, w = t >> 6, cl = lane & 15, g = lane >> 4;
  int rg = w & 3, nh = w >> 2;
  const size_t KSTR = (size_t)64 * 32768;
  size_t tb = ((size_t)(b * 8 + c)) * 32768 + it * 4096;
  // prologue: stage both t1 tiles into loop buffers, hoist A-frags to regs
  stageT(bx0, t1h + tb, 64, t, 512);
  stageT(bx1, t1l + tb, 64, t, 512);
  stageT(bt0, t1h + tb + KSTR, 64, t, 512);
  stageT(bt1, t1l + tb + KSTR, 64, t, 512);
  __syncthreads();
  bf16x8 tf0h[2], tf0l[2], tf1h[2], tf1l[2];
#pragma unroll
  for (int ks = 0; ks < 2; ks++) {
    tf0h[ks] = frag64(bx0, rg * 16, ks, lane);
    tf0l[ks] = frag64(bx1, rg * 16, ks, lane);
    tf1h[ks] = frag64(bt0, rg * 16, ks, lane);
    tf1l[ks] = frag64(bt1, rg * 16, ks, lane);
  }
  float mi_[4], s_run[4];
#pragma unroll
  for (int r = 0; r < 4; r++) {
    mi_[r] = (mask[b * 512 + it * 64 + rg * 16 + g * 4 + r] != 0) ? 1.f : 0.f;
    s_run[r] = 0.f;
  }
  f32x4 accU[2] = {{0.f, 0.f, 0.f, 0.f}, {0.f, 0.f, 0.f, 0.f}};
  f32x4 accL[2] = {{0.f, 0.f, 0.f, 0.f}, {0.f, 0.f, 0.f, 0.f}};

#pragma unroll 1
  for (int jt = 0; jt < 8; jt++) {
    __syncthreads();  // protects hoist reads (jt=0) / prior GEMM reads
    stageT(bx0, qzh + (b * 512 + jt * 64) * 64, 64, t, 512);
    stageT(bx1, qzl + (b * 512 + jt * 64) * 64, 64, t, 512);
    stageT(bt0, qzTh + (size_t)b * 32768 + jt * 64, 512, t, 512);
    stageT(bt1, qzTl + (size_t)b * 32768 + jt * 64, 512, t, 512);
    __syncthreads();
    if (jt > it) {
      A1_PASS(tf0h, tf0l, accU, true)
    } else if (jt < it) {
      A1_PASS(tf1h, tf1l, accL, false)
    } else {
      A1_PASS(tf0h, tf0l, accU, true)
      __syncthreads();  // qh_s rewrite vs GEMM2 reads
      A1_PASS(tf1h, tf1l, accL, false)
    }
  }
  // epilogue: one reduction for s, then scale + store
#pragma unroll
  for (int r = 0; r < 4; r++) {
    float s = s_run[r];
    s += __shfl_xor(s, 1);
    s += __shfl_xor(s, 2);
    s += __shfl_xor(s, 4);
    s += __shfl_xor(s, 8);
    s_run[r] = s;
  }
  __syncthreads();
  if (cl == 0) {
#pragma unroll
    for (int r = 0; r < 4; r++) ps[nh * 64 + rg * 16 + g * 4 + r] = s_run[r];
  }
  __syncthreads();
#pragma unroll
  for (int r = 0; r < 4; r++) {
    int row = rg * 16 + g * 4 + r;
    float stot = ps[row] + ps[64 + row];
    float scale = mi_[r] / stot;
    int grow = it * 64 + row;
#pragma unroll
    for (int ntl = 0; ntl < 2; ntl++) {
      size_t o0 = ((size_t)b * 512 + grow) * 1024 + c * 64 +
                  (nh * 2 + ntl) * 16 + cl;
      u16 h, l;
      split2(accU[ntl][r] * scale, h, l);
      A1h[o0] = h;
      A1l[o0] = l;
      split2(accL[ntl][r] * scale, h, l);
      A1h[o0 + 512] = h;
      A1l[o0 + 512] = l;
    }
    if (nh == 0 && cl == 0) sts[(b * 8 + c) * 512 + grow] = stot;
  }
}

// ---------------------------------------------------------------------------
// a2: A2[b][j][kk,c,a] = sum_i qh[kk][i][j]·qz[i][a]  (recompute, uses sts)
// ---------------------------------------------------------------------------
#define A2_PASS(ACC, KKis0)                                                  \
  {                                                                          \
    f32x4 accq0 = {0.f, 0.f, 0.f, 0.f}, accq1 = {0.f, 0.f, 0.f, 0.f};       \
    _Pragma("unroll") for (int ks = 0; ks < 2; ks++) {                       \
      bf16x8 bh0 = frag64(tsx0, (nh * 2) * 16, ks, lane);                    \
      bf16x8 bl0 = frag64(tsx1, (nh * 2) * 16, ks, lane);                    \
      bf16x8 bh1 = frag64(tsx0, (nh * 2 + 1) * 16, ks, lane);                \
      bf16x8 bl1 = frag64(tsx1, (nh * 2 + 1) * 16, ks, lane);                \
      accq0 = MFMA(afh[ks], bh0, accq0);                                     \
      accq0 = MFMA(afh[ks], bl0, accq0);                                     \
      accq0 = MFMA(afl[ks], bh0, accq0);                                     \
      accq1 = MFMA(afh[ks], bh1, accq1);                                     \
      accq1 = MFMA(afh[ks], bl1, accq1);                                     \
      accq1 = MFMA(afl[ks], bh1, accq1);                                     \
    }                                                                        \
    _Pragma("unroll") for (int ntl = 0; ntl < 2; ntl++) {                    \
      int col = (nh * 2 + ntl) * 16 + cl;                                    \
      int ig = ii * 64 + col;                                                \
      float sim = simi[col];                                                 \
      _Pragma("unroll") for (int r = 0; r < 4; r++) {                        \
        int row = rg * 16 + g * 4 + r;                                       \
        int jg = jt * 64 + row;                                              \
        float e = __expf(ntl ? accq1[r] : accq0[r]);                         \
        bool keep = KKis0 ? (jg > ig) : (jg < ig);                           \
        float q = keep ? e * sim * mjrow[r] : 0.f;                           \
        int byte = (row * 128 + col * 2) ^ ((row & 7) << 4);                 \
        *(u16*)((char*)qh_s + byte) = f2b(q);                                \
      }                                                                      \
    }                                                                        \
    __syncthreads();                                                         \
    _Pragma("unroll") for (int ks = 0; ks < 2; ks++) {                       \
      bf16x8 ah = frag64(qh_s, rg * 16, ks, lane);                           \
      _Pragma("unroll") for (int ntl = 0; ntl < 2; ntl++) {                  \
        int nt = nh * 2 + ntl;                                               \
        bf16x8 bh = frag64(bt0, nt * 16, ks, lane);                          \
        bf16x8 bl = frag64(bt1, nt * 16, ks, lane);                          \
        ACC[ntl] = MFMA(ah, bh, ACC[ntl]);                                   \
        ACC[ntl] = MFMA(ah, bl, ACC[ntl]);                                   \
      }                                                                      \
    }                                                                        \
  }

__global__ __launch_bounds__(512, 4) void a2_kernel(
    const u16* __restrict__ t1h, const u16* __restrict__ t1l,
    const u16* __restrict__ qzh, const u16* __restrict__ qzl,
    const u16* __restrict__ qzTh, const u16* __restrict__ qzTl,
    const float* __restrict__ sts, const int* __restrict__ mask,
    u16* __restrict__ A2h, u16* __restrict__ A2l) {
  int blk = blockIdx.x;  // b*64 + c*8 + jt
  int jt = blk & 7, c = (blk >> 3) & 7, b = blk >> 6;
  __shared__ u16 smem[20608];  // 41216 B
  u16* tsx0 = smem;            // t1 tile hi
  u16* tsx1 = smem + 4096;     // t1 tile lo
  u16* bt0 = smem + 8192;      // qzT hi
  u16* bt1 = smem + 12288;     // qzT lo
  u16* qh_s = smem + 16384;    // qhT hi
  float* simi = (float*)(smem + 20480);  // [64] = mi/s per i
  int t = threadIdx.x, lane = t & 63, w = t >> 6, cl = lane & 15, g = lane >> 4;
  int rg = w & 3, nh = w >> 2;
  const size_t KSTR = (size_t)64 * 32768;
  size_t tbb = ((size_t)(b * 8 + c)) * 32768;
  // prologue: stage qz[jt] into tsx area, hoist A-frags
  stageT(tsx0, qzh + (b * 512 + jt * 64) * 64, 64, t, 512);
  stageT(tsx1, qzl + (b * 512 + jt * 64) * 64, 64, t, 512);
  __syncthreads();
  bf16x8 afh[2], afl[2];
#pragma unroll
  for (int ks = 0; ks < 2; ks++) {
    afh[ks] = frag64(tsx0, rg * 16, ks, lane);
    afl[ks] = frag64(tsx1, rg * 16, ks, lane);
  }
  float mjrow[4];
#pragma unroll
  for (int r = 0; r < 4; r++) {
    int jg = jt * 64 + rg * 16 + g * 4 + r;
    mjrow[r] = (mask[b * 512 + jg] != 0) ? 1.f : 0.f;
  }
  f32x4 accU[2] = {{0.f, 0.f, 0.f, 0.f}, {0.f, 0.f, 0.f, 0.f}};
  f32x4 accL[2] = {{0.f, 0.f, 0.f, 0.f}, {0.f, 0.f, 0.f, 0.f}};

#pragma unroll 1
  for (int ii = 0; ii < 8; ii++) {
    int diag = (ii == jt);
    int kk0 = (ii < jt) ? 0 : 1;
    __syncthreads();
    {
      size_t tsrc = tbb + ii * 4096 + ((diag || kk0 == 0) ? 0 : KSTR);
      stageT(tsx0, t1h + tsrc, 64, t, 512);
      stageT(tsx1, t1l + tsrc, 64, t, 512);
    }
    stageT(bt0, qzTh + (size_t)b * 32768 + ii * 64, 512, t, 512);
    stageT(bt1, qzTl + (size_t)b * 32768 + ii * 64, 512, t, 512);
    if (t < 64) {
      int ig = ii * 64 + t;
      float mi = (mask[b * 512 + ig] != 0) ? 1.f : 0.f;
      simi[t] = mi / sts[(b * 8 + c) * 512 + ig];
    }
    __syncthreads();
    if (diag) {
      A2_PASS(accU, true)
      __syncthreads();
      stageT(tsx0, t1h + tbb + ii * 4096 + KSTR, 64, t, 512);
      stageT(tsx1, t1l + tbb + ii * 4096 + KSTR, 64, t, 512);
      __syncthreads();
      A2_PASS(accL, false)
    } else if (kk0 == 0) {
      A2_PASS(accU, true)
    } else {
      A2_PASS(accL, false)
    }
  }
#pragma unroll
  for (int r = 0; r < 4; r++) {
    int row = jt * 64 + rg * 16 + g * 4 + r;
#pragma unroll
    for (int ntl = 0; ntl < 2; ntl++) {
      size_t o0 = ((size_t)b * 512 + row) * 1024 + c * 64 +
                  (nh * 2 + ntl) * 16 + cl;
      u16 h, l;
      split2(accU[ntl][r], h, l);
      A2h[o0] = h;
      A2l[o0] = l;
      split2(accL[ntl][r], h, l);
      A2h[o0 + 512] = h;
      A2l[o0 + 512] = l;
    }
  }
}

// ---------------------------------------------------------------------------
// F{1,2} partials: Fp[part][b][m][n] = sum_{K part} A[b][m][K]·Tp[n][K]
// blk = sel*512 + part*64 + b*8 + it  (sel: 0->F1, 1->F2)
// ---------------------------------------------------------------------------
__global__ __launch_bounds__(256) void mm_fz_kernel(
    const u16* __restrict__ A1h, const u16* __restrict__ A1l,
    const u16* __restrict__ A2h, const u16* __restrict__ A2l,
    const u16* __restrict__ T1ph, const u16* __restrict__ T1pl,
    const u16* __restrict__ T2ph, const u16* __restrict__ T2pl,
    float* __restrict__ F1p, float* __restrict__ F2p) {
  int blk = blockIdx.x;
  int it = blk & 7, b = (blk >> 3) & 7, part = (blk >> 6) & 7, sel = blk >> 9;
  const u16* Ah = sel ? A2h : A1h;
  const u16* Al = sel ? A2l : A1l;
  const u16* Bh = sel ? T2ph : T1ph;
  const u16* Bl = sel ? T2pl : T1pl;
  float* Fp = (sel ? F2p : F1p) + (size_t)part * (BB * 512 * 64);
  __shared__ u16 ah_s[4096], al_s[4096], bh_s[4096], bl_s[4096];
  int t = threadIdx.x, lane = t & 63, w = t >> 6;
  f32x4 acc[4] = ACC_INIT;
  size_t abase = ((size_t)b * 512 + it * 64) * 1024;
  for (int cc2 = 0; cc2 < 2; cc2++) {
    int ch = part * 2 + cc2;
    __syncthreads();
    stageT(ah_s, Ah + abase + ch * 64, 1024, t, 256);
    stageT(al_s, Al + abase + ch * 64, 1024, t, 256);
    stageT(bh_s, Bh + ch * 64, 1024, t, 256);
    stageT(bl_s, Bl + ch * 64, 1024, t, 256);
    __syncthreads();
    for (int ks = 0; ks < 2; ks++) {
      bf16x8 ah = frag64(ah_s, w * 16, ks, lane);
      bf16x8 al = frag64(al_s, w * 16, ks, lane);
#pragma unroll
      for (int nt = 0; nt < 4; nt++)
        mfma3(acc[nt], ah, al, frag64(bh_s, nt * 16, ks, lane),
              frag64(bl_s, nt * 16, ks, lane));
    }
  }
  int rb = (lane >> 4) * 4, cl = lane & 15;
#pragma unroll
  for (int nt = 0; nt < 4; nt++)
#pragma unroll
    for (int r = 0; r < 4; r++)
      Fp[((size_t)b * 512 + it * 64 + w * 16 + rb + r) * 64 + nt * 16 + cl] =
          acc[nt][r];
}

// ---------------------------------------------------------------------------
// fused q_g + F_Z:  out = x + sum_p F1p + sum_p F2p + softmax(qz@gw^T)*m1 @ gw
// ---------------------------------------------------------------------------
__global__ __launch_bounds__(256) void fzqg_kernel(
    const float* __restrict__ x, const float* __restrict__ F1p,
    const float* __restrict__ F2p, const float* __restrict__ qz,
    const float* __restrict__ gw, const int* __restrict__ mask,
    float* __restrict__ out) {
  int blk = blockIdx.x;
  int ic = blk & 15, b = blk >> 4;
  int i0 = ic * 32;
  int t = threadIdx.x;
  __shared__ float gw_s[64][65];
  __shared__ float qz_s[32][64];
  __shared__ float fg_s[32][65];
  for (int p = t; p < 4096; p += 256) gw_s[p >> 6][p & 63] = gw[p];
  for (int p = t; p < 2048; p += 256) {
    int il = p >> 6, a = p & 63;
    qz_s[il][a] = qz[(b * LL + i0 + il) * 64 + a];
  }
  __syncthreads();
  int gcol = t & 63, il0 = t >> 6;
#pragma unroll
  for (int s = 0; s < 8; s++) {
    int il = il0 + 4 * s;
    float acc = 0.f;
    for (int a = 0; a < 64; a++) acc += qz_s[il][a] * gw_s[gcol][a];
    fg_s[il][gcol] = acc;
  }
  __syncthreads();
  {
    int r = t >> 3, k = t & 7;
    float v[8];
#pragma unroll
    for (int u = 0; u < 8; u++) v[u] = fg_s[r][k * 8 + u];
    float m = v[0];
#pragma unroll
    for (int u = 1; u < 8; u++) m = fmaxf(m, v[u]);
    for (int o = 1; o < 8; o <<= 1) m = fmaxf(m, __shfl_xor(m, o));
    float s = 0.f;
#pragma unroll
    for (int u = 0; u < 8; u++) s += __expf(v[u] - m);
    for (int o = 1; o < 8; o <<= 1) s += __shfl_xor(s, o);
    float mi = (mask[b * LL + i0 + r] != 0) ? 1.f : 0.f;
    float inv = mi / s;
#pragma unroll
    for (int u = 0; u < 8; u++) fg_s[r][k * 8 + u] = __expf(v[u] - m) * inv;
  }
  __syncthreads();
  int a = t & 63;
#pragma unroll
  for (int s = 0; s < 8; s++) {
    int il = il0 + 4 * s;
    float acc = 0.f;
    for (int g2 = 0; g2 < 64; g2++) acc += fg_s[il][g2] * gw_s[g2][a];
    size_t idx = (size_t)(b * LL + i0 + il) * 64 + a;
    float fs = x[idx] + acc;
    for (int p = 0; p < NP; p++)
      fs += F1p[(size_t)p * (BB * 512 * 64) + idx] +
            F2p[(size_t)p * (BB * 512 * 64) + idx];
    out[idx] = fs;
  }
}

// ---------------------------------------------------------------------------
extern "C" void kernel_launch(void* const* d_in, const int* in_sizes, int n_in,
                              void* d_out, int out_size, void* d_ws,
                              size_t ws_size, hipStream_t stream) {
  const float* x = (const float*)d_in[0];
  const int* mask = (const int*)d_in[1];
  const float* ternary = (const float*)d_in[2];
  const float* gw = (const float*)d_in[3];
  float* out = (float*)d_out;

  char* w = (char*)d_ws;
  float* qz_f = (float*)(w);                           // 1 MB
  float* Q_Z = (float*)(w + (1 << 20));                // 1 MB
  u16* qzh = (u16*)(w + (2 << 20));                    // 512 KB
  u16* qzl = (u16*)(w + (2 << 20) + (512 << 10));      // 512 KB
  u16* qzTh = (u16*)(w + (3 << 20));                   // 512 KB
  u16* qzTl = (u16*)(w + (3 << 20) + (512 << 10));     // 512 KB
  u16* TBh = (u16*)(w + (4 << 20));                    // 6 x 128 KB
  u16* TBl = (u16*)(w + (4 << 20) + (128 << 10));
  u16* T1ph = (u16*)(w + (4 << 20) + (256 << 10));
  u16* T1pl = (u16*)(w + (4 << 20) + (384 << 10));
  u16* T2ph = (u16*)(w + (4 << 20) + (512 << 10));
  u16* T2pl = (u16*)(w + (4 << 20) + (640 << 10));
  float* sts = (float*)(w + (5 << 20));                // 128 KB
  float* F1p = (float*)(w + (6 << 20));                // 8 MB
  float* F2p = (float*)(w + (14 << 20));               // 8 MB
  u16* t1h = (u16*)(w + (22 << 20));                   // 8 MB
  u16* t1l = (u16*)(w + (30 << 20));                   // 8 MB
  u16* A1h = (u16*)(w + (38 << 20));                   // 8 MB
  u16* A1l = (u16*)(w + (46 << 20));                   // 8 MB
  u16* A2h = (u16*)(w + (54 << 20));                   // 8 MB
  u16* A2l = (u16*)(w + (62 << 20));                   // 8 MB -> 70 MB total

  repack_kernel<<<256, 256, 0, stream>>>(ternary, TBh, TBl, T1ph, T1pl, T2ph,
                                         T2pl);
  const float* zin = x;
  for (int iter = 0; iter < NITER; iter++) {
    softmax_z_kernel<<<BB * LL, 64, 0, stream>>>(zin, mask, qz_f, qzh, qzl);
    qzT_kernel<<<128, 256, 0, stream>>>(qzh, qzl, qzTh, qzTl);
    mm_t1_kernel<<<1024, 256, 0, stream>>>(qzh, qzl, TBh, TBl, t1h, t1l);
    a1_kernel<<<512, 512, 0, stream>>>(t1h, t1l, qzh, qzl, qzTh, qzTl, mask,
                                       sts, A1h, A1l);
    a2_kernel<<<512, 512, 0, stream>>>(t1h, t1l, qzh, qzl, qzTh, qzTl, sts,
                                       mask, A2h, A2l);
    mm_fz_kernel<<<1024, 256, 0, stream>>>(A1h, A1l, A2h, A2l, T1ph, T1pl,
                                           T2ph, T2pl, F1p, F2p);
    float* zout = (iter == NITER - 1) ? out : Q_Z;
    fzqg_kernel<<<128, 256, 0, stream>>>(x, F1p, F2p, qz_f, gw, mask, zout);
    zin = Q_Z;
  }
}